// Round 9
// baseline (652.032 us; speedup 1.0000x reference)
//
#include <hip/hip_runtime.h>
#include <math.h>

typedef unsigned short u16;
typedef __attribute__((ext_vector_type(8))) short bf16x8;
typedef __attribute__((ext_vector_type(4))) float f32x4;
typedef __attribute__((ext_vector_type(16))) float f32x16;

#define B_ 16
#define L_ 8192
#define D_ 256
#define H_ 8
#define NL_ 4
#define DFF_ 512
#define S_ 1024
#define L1_ 2048
#define MROWS_ 16384

__device__ __forceinline__ u16 f2bf(float f) {
    unsigned u = __float_as_uint(f);
    unsigned r = (u + 0x7fffu + ((u >> 16) & 1u)) >> 16;   // RNE
    return (u16)r;
}
__device__ __forceinline__ float fexp2(float x) {
    return __builtin_amdgcn_exp2f(x);    // raw v_exp_f32 (2^x)
}
__device__ __forceinline__ unsigned cvtpk(float a, float b) {
    unsigned r;
    asm("v_cvt_pk_bf16_f32 %0, %1, %2" : "=v"(r) : "v"(a), "v"(b));
    return r;
}
__device__ __forceinline__ void pl32swap(unsigned& dst, unsigned& src) {
    asm volatile("v_permlane32_swap_b32 %0, %1" : "+v"(dst), "+v"(src));
}
// bank swizzle involution: bits 4-5 ^= bits 7-8 (16B-granule permute within 2KB tile)
__device__ __forceinline__ int swz16(int b) { return b ^ ((b >> 3) & 0x18); }

// ---- async global->LDS (16B per lane) ----
typedef __attribute__((address_space(1))) const void gvoid;
typedef __attribute__((address_space(3))) void lvoid;
__device__ __forceinline__ void gll16(const void* g, void* l) {
    __builtin_amdgcn_global_load_lds((gvoid*)g, (lvoid*)l, 16, 0, 0);
}
__device__ __forceinline__ void stage64(const u16* src, int ld, u16* lds, int tid) {
    gll16(src + (size_t)(tid >> 2) * ld + (tid & 3) * 8, lds + (tid >> 6) * 512);
}

// ---------------- fused conv1 + im2col: x -> A2 bf16 [B*S][128] ----------------
__global__ __launch_bounds__(256) void conv1_im2col_kernel(const float* __restrict__ x,
                                                           const float* __restrict__ w,
                                                           const float* __restrict__ bias,
                                                           u16* __restrict__ A2) {
    int idx = blockIdx.x * 256 + threadIdx.x;   // 2M
    int k = idx & 127, row = idx >> 7;
    int c = k >> 2, j = k & 3;
    int b = row >> 10, s = row & 1023;
    int p = s * 2 - 1 + j;                      // conv1 output position
    float v = 0.f;
    if (p >= 0 && p < L1_) {
        float acc = bias[c];
        int base = p * 4 - 2;
#pragma unroll
        for (int ci = 0; ci < 2; ++ci) {
            const float* xr = x + ((size_t)(b * 2 + ci)) * L_;
            const float* wr = w + (c * 2 + ci) * 8;
#pragma unroll
            for (int jj = 0; jj < 8; ++jj) {
                int pos = base + jj;
                if (pos >= 0 && pos < L_) acc += xr[pos] * wr[jj];
            }
        }
        v = fmaxf(acc, 0.f);
    }
    A2[idx] = f2bf(v);
}

// ---------------- one-shot pack of all weights / PE / biases / zeros ----------------
__global__ __launch_bounds__(256) void pack_all(const float* __restrict__ wq,
                                                const float* __restrict__ wk,
                                                const float* __restrict__ wv,
                                                const float* __restrict__ wo,
                                                const float* __restrict__ ff_w1,
                                                const float* __restrict__ ff_w2,
                                                const float* __restrict__ conv2_w,
                                                const float* __restrict__ bq,
                                                const float* __restrict__ bk,
                                                const float* __restrict__ bv,
                                                u16* __restrict__ qkvT, u16* __restrict__ woT,
                                                u16* __restrict__ ff1T, u16* __restrict__ ff2T,
                                                u16* __restrict__ w2cT,
                                                float* __restrict__ pe, float* __restrict__ bqkv,
                                                float* __restrict__ pooled, float qscale) {
    int id = blockIdx.x * 256 + threadIdx.x;
    if (id < 786432) {                       // qkvT [l][row<768][k]
        int l = id / 196608, j = id % 196608;
        int row = j >> 8, k = j & 255;
        const float* src; float sc = 1.f; int n;
        if (row < 256) { src = wq; n = row; sc = qscale; }
        else if (row < 512) { src = wk; n = row - 256; }
        else { src = wv; n = row - 512; }
        qkvT[id] = f2bf(src[((size_t)l * 256 + k) * 256 + n] * sc);
        return;
    }
    id -= 786432;
    if (id < 262144) {                       // woT
        int l = id >> 16, j = id & 65535;
        int n = j >> 8, k = j & 255;
        woT[id] = f2bf(wo[((size_t)l * 256 + k) * 256 + n]);
        return;
    }
    id -= 262144;
    if (id < 524288) {                       // ff1T: N=512, K=256
        int l = id >> 17, j = id & 131071;
        int n = j >> 8, k = j & 255;
        ff1T[id] = f2bf(ff_w1[((size_t)l * 256 + k) * 512 + n]);
        return;
    }
    id -= 524288;
    if (id < 524288) {                       // ff2T: N=256, K=512
        int l = id >> 17, j = id & 131071;
        int n = j >> 9, k = j & 511;
        ff2T[id] = f2bf(ff_w2[((size_t)l * 512 + k) * 256 + n]);
        return;
    }
    id -= 524288;
    if (id < 32768) { w2cT[id] = f2bf(conv2_w[id]); return; }
    id -= 32768;
    if (id < 262144) {                       // PE table
        int s = id >> 8, d = id & 255;
        int i2 = d & ~1;
        float div = expf((float)i2 * (-9.210340371976184f / 256.f));
        float arg = (float)s * div;
        pe[id] = (d & 1) ? cosf(arg) : sinf(arg);
        return;
    }
    id -= 262144;
    if (id < 3072) {                         // fused qkv bias
        int l = id / 768, n = id % 768;
        const float* src = (n < 256) ? bq : (n < 512) ? bk : bv;
        float sc = (n < 256) ? qscale : 1.f;
        bqkv[id] = src[l * 256 + (n & 255)] * sc;
        return;
    }
    id -= 3072;
    if (id < 4096) pooled[id] = 0.f;
}

// ---------------- MFMA GEMM 128x128 ----------------
// EP=1: bias+relu -> bf16 (ld N). EP=2: relu(bias)+PE -> h fp32 + hb bf16 (conv2).
// EP=3: qkv: col<256 -> Q bf16 ld256; 256-511 -> K tiles [bh][kt][32key][32dim] (src-swizzled);
//        >=512 -> V^T tiles [bh][kt][32dim][32s] (src-swizzled).
template <int EP>
__global__ __launch_bounds__(256) void mfma_gemm128(const u16* __restrict__ A, int lda,
                                                    const u16* __restrict__ WT,
                                                    const float* __restrict__ bias,
                                                    const float* __restrict__ pe,
                                                    float* __restrict__ hout,
                                                    u16* __restrict__ outB,
                                                    u16* __restrict__ ktout,
                                                    u16* __restrict__ vtout,
                                                    int N, int K) {
    __shared__ u16 Alds[128 * 32];
    __shared__ u16 Blds[128 * 32];
    int tid = threadIdx.x;
    int lane = tid & 63, w = tid >> 6;
    int lo = lane & 15, hi = lane >> 4;
    int m0 = blockIdx.y * 128;
    int n0 = blockIdx.x * 128;
    int wm = (w >> 1) * 64, wn = (w & 1) * 64;
    f32x4 acc[4][4];
#pragma unroll
    for (int i = 0; i < 4; ++i)
#pragma unroll
        for (int j = 0; j < 4; ++j) acc[i][j] = (f32x4){0.f, 0.f, 0.f, 0.f};

    for (int k0 = 0; k0 < K; k0 += 32) {
        stage64(A + (size_t)m0 * lda + k0, lda, Alds, tid);
        stage64(A + (size_t)(m0 + 64) * lda + k0, lda, Alds + 2048, tid);
        stage64(WT + (size_t)n0 * K + k0, K, Blds, tid);
        stage64(WT + (size_t)(n0 + 64) * K + k0, K, Blds + 2048, tid);
        __syncthreads();
        bf16x8 af[4], bfr[4];
#pragma unroll
        for (int mf = 0; mf < 4; ++mf) af[mf] = *(bf16x8*)&Alds[(wm + mf * 16 + lo) * 32 + hi * 8];
#pragma unroll
        for (int nf = 0; nf < 4; ++nf) bfr[nf] = *(bf16x8*)&Blds[(wn + nf * 16 + lo) * 32 + hi * 8];
#pragma unroll
        for (int mf = 0; mf < 4; ++mf)
#pragma unroll
            for (int nf = 0; nf < 4; ++nf)
                acc[mf][nf] = __builtin_amdgcn_mfma_f32_16x16x32_bf16(af[mf], bfr[nf], acc[mf][nf], 0, 0, 0);
        __syncthreads();
    }
#pragma unroll
    for (int mf = 0; mf < 4; ++mf)
#pragma unroll
        for (int nf = 0; nf < 4; ++nf) {
            int col = n0 + wn + nf * 16 + lo;
            float bb = bias[col];
            int rowb = m0 + wm + mf * 16 + hi * 4;
            if (EP == 3 && col >= 512) {
                // V^T tile: elem (d, s) at byte swz16((d*32 + (s&31))*2) within 2KB tile
                int dc = col - 512;
                int bhh = ((rowb >> 10) << 3) + (dc >> 5);
                int s = rowb & 1023;
                unsigned u0 = (unsigned)f2bf(acc[mf][nf][0] + bb) |
                              ((unsigned)f2bf(acc[mf][nf][1] + bb) << 16);
                unsigned u1 = (unsigned)f2bf(acc[mf][nf][2] + bb) |
                              ((unsigned)f2bf(acc[mf][nf][3] + bb) << 16);
                uint2 val = {u0, u1};
                char* tile = (char*)vtout + ((size_t)bhh * 32 + (s >> 5)) * 2048;
                *(uint2*)(tile + swz16(((dc & 31) * 32 + (s & 31)) * 2)) = val;
            } else if (EP == 3 && col >= 256) {
                // K tile: elem (key=s, d) at byte swz16(((s&31)*32 + d)*2)
                int kc = col - 256;
                int bhh = ((rowb >> 10) << 3) + (kc >> 5);
                int s = rowb & 1023;
                char* tile = (char*)ktout + ((size_t)bhh * 32 + (s >> 5)) * 2048;
#pragma unroll
                for (int r = 0; r < 4; ++r)
                    *(u16*)(tile + swz16((((s & 31) + r) * 32 + (kc & 31)) * 2)) =
                        f2bf(acc[mf][nf][r] + bb);
            } else {
#pragma unroll
                for (int r = 0; r < 4; ++r) {
                    float v = acc[mf][nf][r] + bb;
                    if (EP == 1 || EP == 2) v = fmaxf(v, 0.f);
                    if (EP == 2) {
                        v += pe[((rowb + r) & 1023) * 256 + col];
                        hout[(size_t)(rowb + r) * 256 + col] = v;
                        outB[(size_t)(rowb + r) * 256 + col] = f2bf(v);
                    } else if (EP == 3) {
                        outB[(size_t)(rowb + r) * 256 + col] = f2bf(v);
                    } else {
                        outB[(size_t)(rowb + r) * N + col] = f2bf(v);
                    }
                }
            }
        }
}

// ---------------- MFMA GEMM 32x256 + fused residual + LayerNorm (+pool on LAST) ----------------
template <int LAST>
__global__ __launch_bounds__(256) void mfma_gemm_ln(const u16* __restrict__ A, int lda,
                                                    const u16* __restrict__ WT,
                                                    const float* __restrict__ bias,
                                                    const float* __restrict__ resid,
                                                    const float* __restrict__ g,
                                                    const float* __restrict__ b2,
                                                    float* __restrict__ hout,
                                                    u16* __restrict__ hbout,
                                                    float* __restrict__ pooled,
                                                    int K) {
    __shared__ u16 Alds[32 * 32];
    __shared__ u16 Blds[256 * 32];
    __shared__ float red1[32][4];
    __shared__ float red2[32][4];
    int tid = threadIdx.x;
    int lane = tid & 63, w = tid >> 6;
    int lo = lane & 15, hi = lane >> 4;
    int m0 = blockIdx.x * 32;
    int wn = w * 64;
    f32x4 acc[2][4];
#pragma unroll
    for (int i = 0; i < 2; ++i)
#pragma unroll
        for (int j = 0; j < 4; ++j) acc[i][j] = (f32x4){0.f, 0.f, 0.f, 0.f};

    for (int k0 = 0; k0 < K; k0 += 32) {
        if (tid < 128)
            gll16(A + (size_t)(m0 + (tid >> 2)) * lda + k0 + (tid & 3) * 8, Alds + (tid >> 6) * 512);
        stage64(WT + (size_t)0 * K + k0, K, Blds, tid);
        stage64(WT + (size_t)64 * K + k0, K, Blds + 2048, tid);
        stage64(WT + (size_t)128 * K + k0, K, Blds + 4096, tid);
        stage64(WT + (size_t)192 * K + k0, K, Blds + 6144, tid);
        __syncthreads();
        bf16x8 af[2], bfr[4];
#pragma unroll
        for (int mf = 0; mf < 2; ++mf) af[mf] = *(bf16x8*)&Alds[(mf * 16 + lo) * 32 + hi * 8];
#pragma unroll
        for (int nf = 0; nf < 4; ++nf) bfr[nf] = *(bf16x8*)&Blds[(wn + nf * 16 + lo) * 32 + hi * 8];
#pragma unroll
        for (int mf = 0; mf < 2; ++mf)
#pragma unroll
            for (int nf = 0; nf < 4; ++nf)
                acc[mf][nf] = __builtin_amdgcn_mfma_f32_16x16x32_bf16(af[mf], bfr[nf], acc[mf][nf], 0, 0, 0);
        __syncthreads();
    }

#pragma unroll
    for (int mf = 0; mf < 2; ++mf)
#pragma unroll
        for (int nf = 0; nf < 4; ++nf) {
            int col = wn + nf * 16 + lo;
            float bb = bias[col];
#pragma unroll
            for (int r = 0; r < 4; ++r) {
                int row = m0 + mf * 16 + hi * 4 + r;
                acc[mf][nf][r] += bb + resid[(size_t)row * 256 + col];
            }
        }
#pragma unroll
    for (int mf = 0; mf < 2; ++mf)
#pragma unroll
        for (int r = 0; r < 4; ++r) {
            float s1 = acc[mf][0][r] + acc[mf][1][r] + acc[mf][2][r] + acc[mf][3][r];
            float s2 = acc[mf][0][r] * acc[mf][0][r] + acc[mf][1][r] * acc[mf][1][r] +
                       acc[mf][2][r] * acc[mf][2][r] + acc[mf][3][r] * acc[mf][3][r];
#pragma unroll
            for (int off = 1; off < 16; off <<= 1) {
                s1 += __shfl_xor(s1, off);
                s2 += __shfl_xor(s2, off);
            }
            if (lo == 0) {
                red1[mf * 16 + hi * 4 + r][w] = s1;
                red2[mf * 16 + hi * 4 + r][w] = s2;
            }
        }
    __syncthreads();
    float colsum[4] = {0.f, 0.f, 0.f, 0.f};
#pragma unroll
    for (int mf = 0; mf < 2; ++mf)
#pragma unroll
        for (int r = 0; r < 4; ++r) {
            int rl = mf * 16 + hi * 4 + r;
            float mean = (red1[rl][0] + red1[rl][1] + red1[rl][2] + red1[rl][3]) * (1.f / 256.f);
            float e2 = (red2[rl][0] + red2[rl][1] + red2[rl][2] + red2[rl][3]) * (1.f / 256.f);
            float rs = rsqrtf(e2 - mean * mean + 1e-5f);
#pragma unroll
            for (int nf = 0; nf < 4; ++nf) {
                int col = wn + nf * 16 + lo;
                float o = (acc[mf][nf][r] - mean) * rs * g[col] + b2[col];
                if (LAST) {
                    colsum[nf] += o;
                } else {
                    hout[(size_t)(m0 + rl) * 256 + col] = o;
                    hbout[(size_t)(m0 + rl) * 256 + col] = f2bf(o);
                }
            }
        }
    if (LAST) {
        int b = m0 >> 10;
#pragma unroll
        for (int nf = 0; nf < 4; ++nf) {
            float cs = colsum[nf];
            cs += __shfl_xor(cs, 16);
            cs += __shfl_xor(cs, 32);
            if (hi == 0) atomicAdd(&pooled[b * 256 + wn + nf * 16 + lo], cs);
        }
    }
}

// ---------------- swapped 32x32 MFMA flash attention, LDS-staged K/V ----------------
// qbuf [B*S][256] (Q, ctx in-place); kt/vt tiles [bh][kt] 2KB each, SOURCE-SWIZZLED so
// linear global_load_lds staging + swizzled ds_read gives bank-optimal access.
__global__ __launch_bounds__(256) void attn_mfma(u16* __restrict__ qbuf,
                                                 const u16* __restrict__ ktiles,
                                                 const u16* __restrict__ vtiles) {
    __shared__ char sbuf[2][4096];   // [buf][K 2KB | V 2KB]
    int tid = threadIdx.x;
    int lane = tid & 63, w = tid >> 6;
    int q = lane & 31, h = lane >> 5;
    int phys = blockIdx.x;
    int bid = (phys & 7) * 128 + (phys >> 3);   // XCD-contiguous: 16 (b,h) per XCD
    int qt = bid & 7, hh = (bid >> 3) & 7, bb = bid >> 6;
    int q0 = qt * 128 + w * 32;
    size_t rowbase = (size_t)bb * S_;

    const u16* qrow = qbuf + (rowbase + q0 + q) * 256 + hh * 32;
    bf16x8 qf0 = *(const bf16x8*)(qrow + h * 8);
    bf16x8 qf1 = *(const bf16x8*)(qrow + 16 + h * 8);

    const char* kt_g = (const char*)(ktiles + (size_t)(bb * 8 + hh) * 32768);
    const char* vt_g = (const char*)(vtiles + (size_t)(bb * 8 + hh) * 32768);
    const char* src_base = (tid < 128 ? kt_g : vt_g) + (tid & 127) * 16;   // already-swizzled data
    char* dst_half = &sbuf[0][0] + (tid >> 6) * 1024;                      // wave-uniform

    int koff0 = swz16(q * 64 + h * 16);
    int koff1 = swz16(q * 64 + 32 + h * 16);

    f32x16 O = {0.f, 0.f, 0.f, 0.f, 0.f, 0.f, 0.f, 0.f, 0.f, 0.f, 0.f, 0.f, 0.f, 0.f, 0.f, 0.f};
    float l = 0.f;

    // prologue: stage tile 0 into buf 0
    gll16(src_base, dst_half);
    __syncthreads();

    int cur = 0;
    for (int t = 0; t < 32; ++t) {
        if (t + 1 < 32) gll16(src_base + (size_t)(t + 1) * 2048, dst_half + (cur ^ 1) * 4096);
        const char* kl = &sbuf[cur][0];
        bf16x8 kf0 = *(const bf16x8*)(kl + koff0);
        bf16x8 kf1 = *(const bf16x8*)(kl + koff1);
        bf16x8 vf0 = *(const bf16x8*)(kl + 2048 + koff0);
        bf16x8 vf1 = *(const bf16x8*)(kl + 2048 + koff1);

        f32x16 S = {0.f, 0.f, 0.f, 0.f, 0.f, 0.f, 0.f, 0.f,
                    0.f, 0.f, 0.f, 0.f, 0.f, 0.f, 0.f, 0.f};
        S = __builtin_amdgcn_mfma_f32_32x32x16_bf16(kf0, qf0, S, 0, 0, 0);
        S = __builtin_amdgcn_mfma_f32_32x32x16_bf16(kf1, qf1, S, 0, 0, 0);
#pragma unroll
        for (int i = 0; i < 16; ++i) S[i] = fexp2(S[i]);
        float t0 = (S[0] + S[1]) + (S[2] + S[3]);
        float t1 = (S[4] + S[5]) + (S[6] + S[7]);
        float t2 = (S[8] + S[9]) + (S[10] + S[11]);
        float t3 = (S[12] + S[13]) + (S[14] + S[15]);
        float ls = (t0 + t1) + (t2 + t3);
        unsigned ua = __float_as_uint(ls), ub = ua;
        pl32swap(ua, ub);
        l += __uint_as_float(ua) + __uint_as_float(ub);

        unsigned pk[8];
#pragma unroll
        for (int i = 0; i < 8; ++i) pk[i] = cvtpk(S[2 * i], S[2 * i + 1]);
        pl32swap(pk[2], pk[0]);
        pl32swap(pk[3], pk[1]);
        pl32swap(pk[6], pk[4]);
        pl32swap(pk[7], pk[5]);
        uint4 t4 = {pk[0], pk[1], pk[2], pk[3]};
        uint4 t5 = {pk[4], pk[5], pk[6], pk[7]};
        bf16x8 pf0 = *(bf16x8*)&t4;
        bf16x8 pf1 = *(bf16x8*)&t5;
        O = __builtin_amdgcn_mfma_f32_32x32x16_bf16(vf0, pf0, O, 0, 0, 0);
        O = __builtin_amdgcn_mfma_f32_32x32x16_bf16(vf1, pf1, O, 0, 0, 0);

        __syncthreads();
        cur ^= 1;
    }

    float inv = 1.f / l;
    u16* orow = qbuf + (rowbase + q0 + q) * 256 + hh * 32;
#pragma unroll
    for (int gg = 0; gg < 4; ++gg) {
        unsigned u0 = cvtpk(O[4 * gg] * inv, O[4 * gg + 1] * inv);
        unsigned u1 = cvtpk(O[4 * gg + 2] * inv, O[4 * gg + 3] * inv);
        uint2 val = {u0, u1};
        *(uint2*)(orow + gg * 8 + h * 4) = val;
    }
}

// ---------------- classifier from pooled sums ----------------
__global__ __launch_bounds__(256) void cls_kernel(const float* __restrict__ pooled,
                                                  const float* __restrict__ w1,
                                                  const float* __restrict__ b1,
                                                  const float* __restrict__ w2,
                                                  const float* __restrict__ b2,
                                                  float* __restrict__ out) {
    int b = blockIdx.x;
    int d = threadIdx.x;
    __shared__ float pl[256];
    __shared__ float hid[128];
    pl[d] = pooled[b * 256 + d] * (1.f / 1024.f);
    __syncthreads();
    if (d < 128) {
        float a = b1[d];
        for (int k = 0; k < 256; ++k) a += pl[k] * w1[k * 128 + d];
        hid[d] = fmaxf(a, 0.f);
    }
    __syncthreads();
    if (d == 0) {
        float a = b2[0];
        for (int k = 0; k < 128; ++k) a += hid[k] * w2[k];
        out[b] = 1.f / (1.f + expf(-a));
    }
}

extern "C" void kernel_launch(void* const* d_in, const int* in_sizes, int n_in,
                              void* d_out, int out_size, void* d_ws, size_t ws_size,
                              hipStream_t stream) {
    const float* x       = (const float*)d_in[0];
    const float* conv1_w = (const float*)d_in[1];
    const float* conv1_b = (const float*)d_in[2];
    const float* conv2_w = (const float*)d_in[3];
    const float* conv2_b = (const float*)d_in[4];
    const float* wq      = (const float*)d_in[5];
    const float* bq      = (const float*)d_in[6];
    const float* wk      = (const float*)d_in[7];
    const float* bk      = (const float*)d_in[8];
    const float* wv      = (const float*)d_in[9];
    const float* bv      = (const float*)d_in[10];
    const float* wo      = (const float*)d_in[11];
    const float* bo      = (const float*)d_in[12];
    const float* ln1_g   = (const float*)d_in[13];
    const float* ln1_b   = (const float*)d_in[14];
    const float* ff_w1   = (const float*)d_in[15];
    const float* ff_b1   = (const float*)d_in[16];
    const float* ff_w2   = (const float*)d_in[17];
    const float* ff_b2   = (const float*)d_in[18];
    const float* ln2_g   = (const float*)d_in[19];
    const float* ln2_b   = (const float*)d_in[20];
    const float* cls_w1  = (const float*)d_in[21];
    const float* cls_b1  = (const float*)d_in[22];
    const float* cls_w2  = (const float*)d_in[23];
    const float* cls_b2  = (const float*)d_in[24];

    char* wsb = (char*)d_ws;
    float* h    = (float*)wsb;
    u16*   hb   = (u16*)(wsb + ((size_t)16 << 20));
    u16*   qbuf = (u16*)(wsb + ((size_t)24 << 20));
    u16*   ktl  = (u16*)(wsb + ((size_t)32 << 20));
    u16*   vtl  = (u16*)(wsb + ((size_t)40 << 20));
    u16*   ffh  = (u16*)(wsb + ((size_t)32 << 20));
    u16*   A2   = (u16*)(wsb + ((size_t)32 << 20));
    float* pe   = (float*)(wsb + ((size_t)48 << 20));
    char*  pkb  = wsb + ((size_t)49 << 20);
    u16*   qkvT = (u16*)pkb;
    u16*   woT  = qkvT + (size_t)4 * 768 * 256;
    u16*   ff1T = woT + (size_t)4 * 256 * 256;
    u16*   ff2T = ff1T + (size_t)4 * 512 * 256;
    u16*   w2cT = ff2T + (size_t)4 * 512 * 256;
    float* bqkv = (float*)(w2cT + 256 * 128);
    float* pooled = bqkv + 4 * 768;

    // fold 1/sqrt(32) * log2(e) into Wq/bq (softmax in exp2 domain)
    const float qscale = 0.17677669529663687f * 1.4426950408889634f;
    pack_all<<<9372, 256, 0, stream>>>(wq, wk, wv, wo, ff_w1, ff_w2, conv2_w, bq, bk, bv,
                                       qkvT, woT, ff1T, ff2T, w2cT, pe, bqkv, pooled, qscale);

    conv1_im2col_kernel<<<8192, 256, 0, stream>>>(x, conv1_w, conv1_b, A2);
    mfma_gemm128<2><<<dim3(2, 128), 256, 0, stream>>>(A2, 128, w2cT, conv2_b, pe, h, hb,
                                                      nullptr, nullptr, 256, 128);

    for (int l = 0; l < NL_; ++l) {
        const u16* qkvT_l = qkvT + (size_t)l * 768 * 256;
        const u16* woT_l  = woT + (size_t)l * 256 * 256;
        const u16* ff1T_l = ff1T + (size_t)l * 512 * 256;
        const u16* ff2T_l = ff2T + (size_t)l * 256 * 512;

        mfma_gemm128<3><<<dim3(6, 128), 256, 0, stream>>>(hb, 256, qkvT_l, bqkv + l * 768,
                                                          nullptr, nullptr, qbuf, ktl, vtl, 256, 256);
        attn_mfma<<<1024, 256, 0, stream>>>(qbuf, ktl, vtl);
        mfma_gemm_ln<0><<<512, 256, 0, stream>>>(qbuf, 256, woT_l, bo + l * 256, h,
                                                 ln1_g + l * 256, ln1_b + l * 256, h, hb, nullptr, 256);
        mfma_gemm128<1><<<dim3(4, 128), 256, 0, stream>>>(hb, 256, ff1T_l, ff_b1 + l * 512,
                                                          nullptr, nullptr, ffh, nullptr, nullptr, 512, 256);
        if (l < NL_ - 1) {
            mfma_gemm_ln<0><<<512, 256, 0, stream>>>(ffh, 512, ff2T_l, ff_b2 + l * 256, h,
                                                     ln2_g + l * 256, ln2_b + l * 256, h, hb, nullptr, 512);
        } else {
            mfma_gemm_ln<1><<<512, 256, 0, stream>>>(ffh, 512, ff2T_l, ff_b2 + l * 256, h,
                                                     ln2_g + l * 256, ln2_b + l * 256, h, hb, pooled, 512);
        }
    }

    cls_kernel<<<B_, 256, 0, stream>>>(pooled, cls_w1, cls_b1, cls_w2, cls_b2, (float*)d_out);
}

// Round 10
// 598.601 us; speedup vs baseline: 1.0893x; 1.0893x over previous
//
#include <hip/hip_runtime.h>
#include <math.h>

typedef unsigned short u16;
typedef __attribute__((ext_vector_type(8))) short bf16x8;
typedef __attribute__((ext_vector_type(4))) float f32x4;
typedef __attribute__((ext_vector_type(16))) float f32x16;

#define B_ 16
#define L_ 8192
#define D_ 256
#define H_ 8
#define NL_ 4
#define DFF_ 512
#define S_ 1024
#define L1_ 2048
#define MROWS_ 16384

__device__ __forceinline__ u16 f2bf(float f) {
    unsigned u = __float_as_uint(f);
    unsigned r = (u + 0x7fffu + ((u >> 16) & 1u)) >> 16;   // RNE
    return (u16)r;
}
__device__ __forceinline__ float fexp2(float x) {
    return __builtin_amdgcn_exp2f(x);    // raw v_exp_f32 (2^x)
}
__device__ __forceinline__ unsigned cvtpk(float a, float b) {
    unsigned r;
    asm("v_cvt_pk_bf16_f32 %0, %1, %2" : "=v"(r) : "v"(a), "v"(b));
    return r;
}
__device__ __forceinline__ void pl32swap(unsigned& dst, unsigned& src) {
    asm volatile("v_permlane32_swap_b32 %0, %1" : "+v"(dst), "+v"(src));
}
// bank swizzle involution: byte bits 4-5 ^= bits 7-8 (within 2KB tile)
__device__ __forceinline__ int swz16(int b) { return b ^ ((b >> 3) & 0x18); }

// ---- async global->LDS (16B per lane) ----
typedef __attribute__((address_space(1))) const void gvoid;
typedef __attribute__((address_space(3))) void lvoid;
__device__ __forceinline__ void gll16(const void* g, void* l) {
    __builtin_amdgcn_global_load_lds((gvoid*)g, (lvoid*)l, 16, 0, 0);
}
__device__ __forceinline__ void stage64(const u16* src, int ld, u16* lds, int tid) {
    gll16(src + (size_t)(tid >> 2) * ld + (tid & 3) * 8, lds + (tid >> 6) * 512);
}

// ---------------- fused conv1 + im2col: x -> A2 bf16 [B*S][128] ----------------
__global__ __launch_bounds__(256) void conv1_im2col_kernel(const float* __restrict__ x,
                                                           const float* __restrict__ w,
                                                           const float* __restrict__ bias,
                                                           u16* __restrict__ A2) {
    int idx = blockIdx.x * 256 + threadIdx.x;   // 2M
    int k = idx & 127, row = idx >> 7;
    int c = k >> 2, j = k & 3;
    int b = row >> 10, s = row & 1023;
    int p = s * 2 - 1 + j;                      // conv1 output position
    float v = 0.f;
    if (p >= 0 && p < L1_) {
        float acc = bias[c];
        int base = p * 4 - 2;
#pragma unroll
        for (int ci = 0; ci < 2; ++ci) {
            const float* xr = x + ((size_t)(b * 2 + ci)) * L_;
            const float* wr = w + (c * 2 + ci) * 8;
#pragma unroll
            for (int jj = 0; jj < 8; ++jj) {
                int pos = base + jj;
                if (pos >= 0 && pos < L_) acc += xr[pos] * wr[jj];
            }
        }
        v = fmaxf(acc, 0.f);
    }
    A2[idx] = f2bf(v);
}

// ---------------- one-shot pack of all weights / PE / biases / zeros ----------------
__global__ __launch_bounds__(256) void pack_all(const float* __restrict__ wq,
                                                const float* __restrict__ wk,
                                                const float* __restrict__ wv,
                                                const float* __restrict__ wo,
                                                const float* __restrict__ ff_w1,
                                                const float* __restrict__ ff_w2,
                                                const float* __restrict__ conv2_w,
                                                const float* __restrict__ bq,
                                                const float* __restrict__ bk,
                                                const float* __restrict__ bv,
                                                u16* __restrict__ qkvT, u16* __restrict__ woT,
                                                u16* __restrict__ ff1T, u16* __restrict__ ff2T,
                                                u16* __restrict__ w2cT,
                                                float* __restrict__ pe, float* __restrict__ bqkv,
                                                float* __restrict__ pooled, float qscale) {
    int id = blockIdx.x * 256 + threadIdx.x;
    if (id < 786432) {                       // qkvT [l][row<768][k]
        int l = id / 196608, j = id % 196608;
        int row = j >> 8, k = j & 255;
        const float* src; float sc = 1.f; int n;
        if (row < 256) { src = wq; n = row; sc = qscale; }
        else if (row < 512) { src = wk; n = row - 256; }
        else { src = wv; n = row - 512; }
        qkvT[id] = f2bf(src[((size_t)l * 256 + k) * 256 + n] * sc);
        return;
    }
    id -= 786432;
    if (id < 262144) {                       // woT
        int l = id >> 16, j = id & 65535;
        int n = j >> 8, k = j & 255;
        woT[id] = f2bf(wo[((size_t)l * 256 + k) * 256 + n]);
        return;
    }
    id -= 262144;
    if (id < 524288) {                       // ff1T: N=512, K=256
        int l = id >> 17, j = id & 131071;
        int n = j >> 8, k = j & 255;
        ff1T[id] = f2bf(ff_w1[((size_t)l * 256 + k) * 512 + n]);
        return;
    }
    id -= 524288;
    if (id < 524288) {                       // ff2T: N=256, K=512
        int l = id >> 17, j = id & 131071;
        int n = j >> 9, k = j & 511;
        ff2T[id] = f2bf(ff_w2[((size_t)l * 512 + k) * 256 + n]);
        return;
    }
    id -= 524288;
    if (id < 32768) { w2cT[id] = f2bf(conv2_w[id]); return; }
    id -= 32768;
    if (id < 262144) {                       // PE table
        int s = id >> 8, d = id & 255;
        int i2 = d & ~1;
        float div = expf((float)i2 * (-9.210340371976184f / 256.f));
        float arg = (float)s * div;
        pe[id] = (d & 1) ? cosf(arg) : sinf(arg);
        return;
    }
    id -= 262144;
    if (id < 3072) {                         // fused qkv bias
        int l = id / 768, n = id % 768;
        const float* src = (n < 256) ? bq : (n < 512) ? bk : bv;
        float sc = (n < 256) ? qscale : 1.f;
        bqkv[id] = src[l * 256 + (n & 255)] * sc;
        return;
    }
    id -= 3072;
    if (id < 4096) pooled[id] = 0.f;
}

// ---------------- MFMA GEMM 128x128 ----------------
// EP=2: relu(bias)+PE -> h fp32 + hb bf16 (conv2).
// EP=3: qkv: col<256 -> Q bf16 ld256; 256-511 -> K tiles [bh][kt][32key][32dim];
//        >=512 -> V^T tiles [bh][kt][32dim][32s].  (linear, un-swizzled)
template <int EP>
__global__ __launch_bounds__(256) void mfma_gemm128(const u16* __restrict__ A, int lda,
                                                    const u16* __restrict__ WT,
                                                    const float* __restrict__ bias,
                                                    const float* __restrict__ pe,
                                                    float* __restrict__ hout,
                                                    u16* __restrict__ outB,
                                                    u16* __restrict__ ktout,
                                                    u16* __restrict__ vtout,
                                                    int N, int K) {
    __shared__ u16 Alds[128 * 32];
    __shared__ u16 Blds[128 * 32];
    int tid = threadIdx.x;
    int lane = tid & 63, w = tid >> 6;
    int lo = lane & 15, hi = lane >> 4;
    int m0 = blockIdx.y * 128;
    int n0 = blockIdx.x * 128;
    int wm = (w >> 1) * 64, wn = (w & 1) * 64;
    f32x4 acc[4][4];
#pragma unroll
    for (int i = 0; i < 4; ++i)
#pragma unroll
        for (int j = 0; j < 4; ++j) acc[i][j] = (f32x4){0.f, 0.f, 0.f, 0.f};

    for (int k0 = 0; k0 < K; k0 += 32) {
        stage64(A + (size_t)m0 * lda + k0, lda, Alds, tid);
        stage64(A + (size_t)(m0 + 64) * lda + k0, lda, Alds + 2048, tid);
        stage64(WT + (size_t)n0 * K + k0, K, Blds, tid);
        stage64(WT + (size_t)(n0 + 64) * K + k0, K, Blds + 2048, tid);
        __syncthreads();
        bf16x8 af[4], bfr[4];
#pragma unroll
        for (int mf = 0; mf < 4; ++mf) af[mf] = *(bf16x8*)&Alds[(wm + mf * 16 + lo) * 32 + hi * 8];
#pragma unroll
        for (int nf = 0; nf < 4; ++nf) bfr[nf] = *(bf16x8*)&Blds[(wn + nf * 16 + lo) * 32 + hi * 8];
#pragma unroll
        for (int mf = 0; mf < 4; ++mf)
#pragma unroll
            for (int nf = 0; nf < 4; ++nf)
                acc[mf][nf] = __builtin_amdgcn_mfma_f32_16x16x32_bf16(af[mf], bfr[nf], acc[mf][nf], 0, 0, 0);
        __syncthreads();
    }
#pragma unroll
    for (int mf = 0; mf < 4; ++mf)
#pragma unroll
        for (int nf = 0; nf < 4; ++nf) {
            int col = n0 + wn + nf * 16 + lo;
            float bb = bias[col];
            int rowb = m0 + wm + mf * 16 + hi * 4;
            if (EP == 3 && col >= 512) {
                int dc = col - 512;
                int bhh = ((rowb >> 10) << 3) + (dc >> 5);
                int s = rowb & 1023;
                unsigned u0 = (unsigned)f2bf(acc[mf][nf][0] + bb) |
                              ((unsigned)f2bf(acc[mf][nf][1] + bb) << 16);
                unsigned u1 = (unsigned)f2bf(acc[mf][nf][2] + bb) |
                              ((unsigned)f2bf(acc[mf][nf][3] + bb) << 16);
                uint2 val = {u0, u1};
                *(uint2*)(vtout + (((size_t)bhh * 32 + (s >> 5)) * 32 + (dc & 31)) * 32 + (s & 31)) = val;
            } else if (EP == 3 && col >= 256) {
                int kc = col - 256;
                int bhh = ((rowb >> 10) << 3) + (kc >> 5);
                int s = rowb & 1023;
                u16* kt_base = ktout + (((size_t)bhh * 32 + (s >> 5)) * 32) * 32;
#pragma unroll
                for (int r = 0; r < 4; ++r)
                    kt_base[((s & 31) + r) * 32 + (kc & 31)] = f2bf(acc[mf][nf][r] + bb);
            } else {
#pragma unroll
                for (int r = 0; r < 4; ++r) {
                    float v = acc[mf][nf][r] + bb;
                    if (EP == 2) v = fmaxf(v, 0.f);
                    if (EP == 2) {
                        v += pe[((rowb + r) & 1023) * 256 + col];
                        hout[(size_t)(rowb + r) * 256 + col] = v;
                        outB[(size_t)(rowb + r) * 256 + col] = f2bf(v);
                    } else {
                        outB[(size_t)(rowb + r) * 256 + col] = f2bf(v);
                    }
                }
            }
        }
}

// ---------------- MFMA GEMM 32x256 + fused residual + LayerNorm (wo path) ----------------
__global__ __launch_bounds__(256) void mfma_gemm_ln(const u16* __restrict__ A, int lda,
                                                    const u16* __restrict__ WT,
                                                    const float* __restrict__ bias,
                                                    const float* __restrict__ resid,
                                                    const float* __restrict__ g,
                                                    const float* __restrict__ b2,
                                                    float* __restrict__ hout,
                                                    u16* __restrict__ hbout,
                                                    int K) {
    __shared__ u16 Alds[32 * 32];
    __shared__ u16 Blds[256 * 32];
    __shared__ float red1[32][4];
    __shared__ float red2[32][4];
    int tid = threadIdx.x;
    int lane = tid & 63, w = tid >> 6;
    int lo = lane & 15, hi = lane >> 4;
    int m0 = blockIdx.x * 32;
    int wn = w * 64;
    f32x4 acc[2][4];
#pragma unroll
    for (int i = 0; i < 2; ++i)
#pragma unroll
        for (int j = 0; j < 4; ++j) acc[i][j] = (f32x4){0.f, 0.f, 0.f, 0.f};

    for (int k0 = 0; k0 < K; k0 += 32) {
        if (tid < 128)
            gll16(A + (size_t)(m0 + (tid >> 2)) * lda + k0 + (tid & 3) * 8, Alds + (tid >> 6) * 512);
        stage64(WT + (size_t)0 * K + k0, K, Blds, tid);
        stage64(WT + (size_t)64 * K + k0, K, Blds + 2048, tid);
        stage64(WT + (size_t)128 * K + k0, K, Blds + 4096, tid);
        stage64(WT + (size_t)192 * K + k0, K, Blds + 6144, tid);
        __syncthreads();
        bf16x8 af[2], bfr[4];
#pragma unroll
        for (int mf = 0; mf < 2; ++mf) af[mf] = *(bf16x8*)&Alds[(mf * 16 + lo) * 32 + hi * 8];
#pragma unroll
        for (int nf = 0; nf < 4; ++nf) bfr[nf] = *(bf16x8*)&Blds[(wn + nf * 16 + lo) * 32 + hi * 8];
#pragma unroll
        for (int mf = 0; mf < 2; ++mf)
#pragma unroll
            for (int nf = 0; nf < 4; ++nf)
                acc[mf][nf] = __builtin_amdgcn_mfma_f32_16x16x32_bf16(af[mf], bfr[nf], acc[mf][nf], 0, 0, 0);
        __syncthreads();
    }

#pragma unroll
    for (int mf = 0; mf < 2; ++mf)
#pragma unroll
        for (int nf = 0; nf < 4; ++nf) {
            int col = wn + nf * 16 + lo;
            float bb = bias[col];
#pragma unroll
            for (int r = 0; r < 4; ++r) {
                int row = m0 + mf * 16 + hi * 4 + r;
                acc[mf][nf][r] += bb + resid[(size_t)row * 256 + col];
            }
        }
#pragma unroll
    for (int mf = 0; mf < 2; ++mf)
#pragma unroll
        for (int r = 0; r < 4; ++r) {
            float s1 = acc[mf][0][r] + acc[mf][1][r] + acc[mf][2][r] + acc[mf][3][r];
            float s2 = acc[mf][0][r] * acc[mf][0][r] + acc[mf][1][r] * acc[mf][1][r] +
                       acc[mf][2][r] * acc[mf][2][r] + acc[mf][3][r] * acc[mf][3][r];
#pragma unroll
            for (int off = 1; off < 16; off <<= 1) {
                s1 += __shfl_xor(s1, off);
                s2 += __shfl_xor(s2, off);
            }
            if (lo == 0) {
                red1[mf * 16 + hi * 4 + r][w] = s1;
                red2[mf * 16 + hi * 4 + r][w] = s2;
            }
        }
    __syncthreads();
#pragma unroll
    for (int mf = 0; mf < 2; ++mf)
#pragma unroll
        for (int r = 0; r < 4; ++r) {
            int rl = mf * 16 + hi * 4 + r;
            float mean = (red1[rl][0] + red1[rl][1] + red1[rl][2] + red1[rl][3]) * (1.f / 256.f);
            float e2 = (red2[rl][0] + red2[rl][1] + red2[rl][2] + red2[rl][3]) * (1.f / 256.f);
            float rs = rsqrtf(e2 - mean * mean + 1e-5f);
#pragma unroll
            for (int nf = 0; nf < 4; ++nf) {
                int col = wn + nf * 16 + lo;
                float o = (acc[mf][nf][r] - mean) * rs * g[col] + b2[col];
                hout[(size_t)(m0 + rl) * 256 + col] = o;
                hbout[(size_t)(m0 + rl) * 256 + col] = f2bf(o);
            }
        }
}

// ---------------- fused ff1 -> relu -> ff2 + residual + LayerNorm (+pool on LAST) ----------------
// A = hb [M][256]; W1T [512][256]; W2T [256][512]. Hidden kept in swizzled LDS tiles.
template <int LAST>
__global__ __launch_bounds__(256) void fused_ff(const u16* __restrict__ A,
                                                const u16* __restrict__ W1T,
                                                const float* __restrict__ b1,
                                                const u16* __restrict__ W2T,
                                                const float* __restrict__ b2,
                                                const float* __restrict__ resid,
                                                const float* __restrict__ g,
                                                const float* __restrict__ bln,
                                                float* __restrict__ hout,
                                                u16* __restrict__ hbout,
                                                float* __restrict__ pooled) {
    __shared__ char hid[16 * 2048];          // [k/32][32 rows][32 k] bf16, swizzled
    __shared__ float red1[32][4];
    __shared__ float red2[32][4];
    int tid = threadIdx.x;
    int lane = tid & 63, w = tid >> 6;
    int lo = lane & 15, hi = lane >> 4;
    int m0 = blockIdx.x * 32;

    // ---- phase 1: hidden = relu(A @ W1 + b1)  (wave w -> hidden cols w*128..+127)
    {
        int wn = w * 128;
        f32x4 acc[2][8];
#pragma unroll
        for (int i = 0; i < 2; ++i)
#pragma unroll
            for (int j = 0; j < 8; ++j) acc[i][j] = (f32x4){0.f, 0.f, 0.f, 0.f};
        for (int k0 = 0; k0 < 256; k0 += 32) {
            bf16x8 af[2], bfr[8];
#pragma unroll
            for (int mf = 0; mf < 2; ++mf)
                af[mf] = *(const bf16x8*)(A + (size_t)(m0 + mf * 16 + lo) * 256 + k0 + hi * 8);
#pragma unroll
            for (int nf = 0; nf < 8; ++nf)
                bfr[nf] = *(const bf16x8*)(W1T + (size_t)(wn + nf * 16 + lo) * 256 + k0 + hi * 8);
#pragma unroll
            for (int mf = 0; mf < 2; ++mf)
#pragma unroll
                for (int nf = 0; nf < 8; ++nf)
                    acc[mf][nf] = __builtin_amdgcn_mfma_f32_16x16x32_bf16(af[mf], bfr[nf], acc[mf][nf], 0, 0, 0);
        }
#pragma unroll
        for (int mf = 0; mf < 2; ++mf)
#pragma unroll
            for (int nf = 0; nf < 8; ++nf) {
                int col = wn + nf * 16 + lo;
                float bb = b1[col];
                char* tile = hid + (col >> 5) * 2048;
                int c2 = (col & 31) * 2;
#pragma unroll
                for (int r = 0; r < 4; ++r) {
                    int row = mf * 16 + hi * 4 + r;
                    *(u16*)(tile + swz16(row * 64 + c2)) = f2bf(fmaxf(acc[mf][nf][r] + bb, 0.f));
                }
            }
    }
    __syncthreads();

    // ---- phase 2: out = hidden @ W2 + b2 + resid -> LN  (wave w -> out cols w*64..+63)
    int wn = w * 64;
    f32x4 acc[2][4];
#pragma unroll
    for (int i = 0; i < 2; ++i)
#pragma unroll
        for (int j = 0; j < 4; ++j) acc[i][j] = (f32x4){0.f, 0.f, 0.f, 0.f};
    for (int k0 = 0; k0 < 512; k0 += 32) {
        bf16x8 af[2], bfr[4];
        const char* tile = hid + (k0 >> 5) * 2048;
#pragma unroll
        for (int mf = 0; mf < 2; ++mf)
            af[mf] = *(const bf16x8*)(tile + swz16((mf * 16 + lo) * 64 + hi * 16));
#pragma unroll
        for (int nf = 0; nf < 4; ++nf)
            bfr[nf] = *(const bf16x8*)(W2T + (size_t)(wn + nf * 16 + lo) * 512 + k0 + hi * 8);
#pragma unroll
        for (int mf = 0; mf < 2; ++mf)
#pragma unroll
            for (int nf = 0; nf < 4; ++nf)
                acc[mf][nf] = __builtin_amdgcn_mfma_f32_16x16x32_bf16(af[mf], bfr[nf], acc[mf][nf], 0, 0, 0);
    }

#pragma unroll
    for (int mf = 0; mf < 2; ++mf)
#pragma unroll
        for (int nf = 0; nf < 4; ++nf) {
            int col = wn + nf * 16 + lo;
            float bb = b2[col];
#pragma unroll
            for (int r = 0; r < 4; ++r) {
                int row = m0 + mf * 16 + hi * 4 + r;
                acc[mf][nf][r] += bb + resid[(size_t)row * 256 + col];
            }
        }
#pragma unroll
    for (int mf = 0; mf < 2; ++mf)
#pragma unroll
        for (int r = 0; r < 4; ++r) {
            float s1 = acc[mf][0][r] + acc[mf][1][r] + acc[mf][2][r] + acc[mf][3][r];
            float s2 = acc[mf][0][r] * acc[mf][0][r] + acc[mf][1][r] * acc[mf][1][r] +
                       acc[mf][2][r] * acc[mf][2][r] + acc[mf][3][r] * acc[mf][3][r];
#pragma unroll
            for (int off = 1; off < 16; off <<= 1) {
                s1 += __shfl_xor(s1, off);
                s2 += __shfl_xor(s2, off);
            }
            if (lo == 0) {
                red1[mf * 16 + hi * 4 + r][w] = s1;
                red2[mf * 16 + hi * 4 + r][w] = s2;
            }
        }
    __syncthreads();
    float colsum[4] = {0.f, 0.f, 0.f, 0.f};
#pragma unroll
    for (int mf = 0; mf < 2; ++mf)
#pragma unroll
        for (int r = 0; r < 4; ++r) {
            int rl = mf * 16 + hi * 4 + r;
            float mean = (red1[rl][0] + red1[rl][1] + red1[rl][2] + red1[rl][3]) * (1.f / 256.f);
            float e2 = (red2[rl][0] + red2[rl][1] + red2[rl][2] + red2[rl][3]) * (1.f / 256.f);
            float rs = rsqrtf(e2 - mean * mean + 1e-5f);
#pragma unroll
            for (int nf = 0; nf < 4; ++nf) {
                int col = wn + nf * 16 + lo;
                float o = (acc[mf][nf][r] - mean) * rs * g[col] + bln[col];
                if (LAST) {
                    colsum[nf] += o;
                } else {
                    hout[(size_t)(m0 + rl) * 256 + col] = o;
                    hbout[(size_t)(m0 + rl) * 256 + col] = f2bf(o);
                }
            }
        }
    if (LAST) {
        int b = m0 >> 10;
#pragma unroll
        for (int nf = 0; nf < 4; ++nf) {
            float cs = colsum[nf];
            cs += __shfl_xor(cs, 16);
            cs += __shfl_xor(cs, 32);
            if (hi == 0) atomicAdd(&pooled[b * 256 + wn + nf * 16 + lo], cs);
        }
    }
}

// ---------------- swapped 32x32 MFMA flash attention (R7 form + setprio) ----------------
__global__ __launch_bounds__(256) void attn_mfma(u16* __restrict__ qbuf,
                                                 const u16* __restrict__ ktiles,
                                                 const u16* __restrict__ vtiles) {
    int tid = threadIdx.x;
    int lane = tid & 63, w = tid >> 6;
    int q = lane & 31, h = lane >> 5;
    int phys = blockIdx.x;
    int bid = (phys & 7) * 128 + (phys >> 3);   // XCD-contiguous: 16 (b,h) per XCD
    int qt = bid & 7, hh = (bid >> 3) & 7, bb = bid >> 6;
    int q0 = qt * 128 + w * 32;
    size_t rowbase = (size_t)bb * S_;

    const u16* qrow = qbuf + (rowbase + q0 + q) * 256 + hh * 32;
    bf16x8 qf0 = *(const bf16x8*)(qrow + h * 8);
    bf16x8 qf1 = *(const bf16x8*)(qrow + 16 + h * 8);

    const u16* kb = ktiles + (size_t)(bb * 8 + hh) * 32768 + q * 32 + h * 8;
    const u16* vb = vtiles + (size_t)(bb * 8 + hh) * 32768 + q * 32 + h * 8;

    f32x16 O = {0.f, 0.f, 0.f, 0.f, 0.f, 0.f, 0.f, 0.f, 0.f, 0.f, 0.f, 0.f, 0.f, 0.f, 0.f, 0.f};
    float l = 0.f;

#define LOADT(d0, d1, d2, d3, t)                         \
    {                                                    \
        const u16* kr = kb + (t) * 1024;                 \
        d0 = *(const bf16x8*)kr;                         \
        d1 = *(const bf16x8*)(kr + 16);                  \
        const u16* vr = vb + (t) * 1024;                 \
        d2 = *(const bf16x8*)vr;                         \
        d3 = *(const bf16x8*)(vr + 16);                  \
    }

#define TILE_BODY(kf0_, kf1_, vf0_, vf1_)                                               \
    {                                                                                   \
        f32x16 S = {0.f, 0.f, 0.f, 0.f, 0.f, 0.f, 0.f, 0.f,                             \
                    0.f, 0.f, 0.f, 0.f, 0.f, 0.f, 0.f, 0.f};                            \
        __builtin_amdgcn_s_setprio(1);                                                  \
        S = __builtin_amdgcn_mfma_f32_32x32x16_bf16(kf0_, qf0, S, 0, 0, 0);             \
        S = __builtin_amdgcn_mfma_f32_32x32x16_bf16(kf1_, qf1, S, 0, 0, 0);             \
        __builtin_amdgcn_s_setprio(0);                                                  \
        _Pragma("unroll") for (int i = 0; i < 16; ++i) S[i] = fexp2(S[i]);              \
        float t0 = (S[0] + S[1]) + (S[2] + S[3]);                                       \
        float t1 = (S[4] + S[5]) + (S[6] + S[7]);                                       \
        float t2 = (S[8] + S[9]) + (S[10] + S[11]);                                     \
        float t3 = (S[12] + S[13]) + (S[14] + S[15]);                                   \
        float ls = (t0 + t1) + (t2 + t3);                                               \
        unsigned ua = __float_as_uint(ls), ub = ua;                                     \
        pl32swap(ua, ub);                                                               \
        l += __uint_as_float(ua) + __uint_as_float(ub);                                 \
        unsigned pk[8];                                                                 \
        _Pragma("unroll") for (int i = 0; i < 8; ++i) pk[i] = cvtpk(S[2 * i], S[2 * i + 1]); \
        pl32swap(pk[2], pk[0]);                                                         \
        pl32swap(pk[3], pk[1]);                                                         \
        pl32swap(pk[6], pk[4]);                                                         \
        pl32swap(pk[7], pk[5]);                                                         \
        uint4 t4 = {pk[0], pk[1], pk[2], pk[3]};                                        \
        uint4 t5 = {pk[4], pk[5], pk[6], pk[7]};                                        \
        bf16x8 pf0 = *(bf16x8*)&t4;                                                     \
        bf16x8 pf1 = *(bf16x8*)&t5;                                                     \
        __builtin_amdgcn_s_setprio(1);                                                  \
        O = __builtin_amdgcn_mfma_f32_32x32x16_bf16(vf0_, pf0, O, 0, 0, 0);             \
        O = __builtin_amdgcn_mfma_f32_32x32x16_bf16(vf1_, pf1, O, 0, 0, 0);             \
        __builtin_amdgcn_s_setprio(0);                                                  \
    }

    bf16x8 ka0, ka1, va0, va1, kb0, kb1, vb0, vb1;
    LOADT(ka0, ka1, va0, va1, 0);
    LOADT(kb0, kb1, vb0, vb1, 1);
    for (int kt = 0; kt < 32; kt += 2) {
        bf16x8 kc0 = ka0, kc1 = ka1, vc0 = va0, vc1 = va1;
        if (kt + 2 < 32) LOADT(kc0, kc1, vc0, vc1, kt + 2);
        TILE_BODY(ka0, ka1, va0, va1);
        bf16x8 kd0 = kb0, kd1 = kb1, vd0 = vb0, vd1 = vb1;
        if (kt + 3 < 32) LOADT(kd0, kd1, vd0, vd1, kt + 3);
        TILE_BODY(kb0, kb1, vb0, vb1);
        ka0 = kc0; ka1 = kc1; va0 = vc0; va1 = vc1;
        kb0 = kd0; kb1 = kd1; vb0 = vd0; vb1 = vd1;
    }
#undef LOADT
#undef TILE_BODY

    float inv = 1.f / l;
    u16* orow = qbuf + (rowbase + q0 + q) * 256 + hh * 32;
#pragma unroll
    for (int gg = 0; gg < 4; ++gg) {
        unsigned u0 = cvtpk(O[4 * gg] * inv, O[4 * gg + 1] * inv);
        unsigned u1 = cvtpk(O[4 * gg + 2] * inv, O[4 * gg + 3] * inv);
        uint2 val = {u0, u1};
        *(uint2*)(orow + gg * 8 + h * 4) = val;
    }
}

// ---------------- classifier from pooled sums ----------------
__global__ __launch_bounds__(256) void cls_kernel(const float* __restrict__ pooled,
                                                  const float* __restrict__ w1,
                                                  const float* __restrict__ b1,
                                                  const float* __restrict__ w2,
                                                  const float* __restrict__ b2,
                                                  float* __restrict__ out) {
    int b = blockIdx.x;
    int d = threadIdx.x;
    __shared__ float pl[256];
    __shared__ float hid[128];
    pl[d] = pooled[b * 256 + d] * (1.f / 1024.f);
    __syncthreads();
    if (d < 128) {
        float a = b1[d];
        for (int k = 0; k < 256; ++k) a += pl[k] * w1[k * 128 + d];
        hid[d] = fmaxf(a, 0.f);
    }
    __syncthreads();
    if (d == 0) {
        float a = b2[0];
        for (int k = 0; k < 128; ++k) a += hid[k] * w2[k];
        out[b] = 1.f / (1.f + expf(-a));
    }
}

extern "C" void kernel_launch(void* const* d_in, const int* in_sizes, int n_in,
                              void* d_out, int out_size, void* d_ws, size_t ws_size,
                              hipStream_t stream) {
    const float* x       = (const float*)d_in[0];
    const float* conv1_w = (const float*)d_in[1];
    const float* conv1_b = (const float*)d_in[2];
    const float* conv2_w = (const float*)d_in[3];
    const float* conv2_b = (const float*)d_in[4];
    const float* wq      = (const float*)d_in[5];
    const float* bq      = (const float*)d_in[6];
    const float* wk      = (const float*)d_in[7];
    const float* bk      = (const float*)d_in[8];
    const float* wv      = (const float*)d_in[9];
    const float* bv      = (const float*)d_in[10];
    const float* wo      = (const float*)d_in[11];
    const float* bo      = (const float*)d_in[12];
    const float* ln1_g   = (const float*)d_in[13];
    const float* ln1_b   = (const float*)d_in[14];
    const float* ff_w1   = (const float*)d_in[15];
    const float* ff_b1   = (const float*)d_in[16];
    const float* ff_w2   = (const float*)d_in[17];
    const float* ff_b2   = (const float*)d_in[18];
    const float* ln2_g   = (const float*)d_in[19];
    const float* ln2_b   = (const float*)d_in[20];
    const float* cls_w1  = (const float*)d_in[21];
    const float* cls_b1  = (const float*)d_in[22];
    const float* cls_w2  = (const float*)d_in[23];
    const float* cls_b2  = (const float*)d_in[24];

    char* wsb = (char*)d_ws;
    float* h    = (float*)wsb;
    u16*   hb   = (u16*)(wsb + ((size_t)16 << 20));
    u16*   qbuf = (u16*)(wsb + ((size_t)24 << 20));
    u16*   ktl  = (u16*)(wsb + ((size_t)32 << 20));
    u16*   vtl  = (u16*)(wsb + ((size_t)40 << 20));
    u16*   A2   = (u16*)(wsb + ((size_t)32 << 20));
    float* pe   = (float*)(wsb + ((size_t)48 << 20));
    char*  pkb  = wsb + ((size_t)49 << 20);
    u16*   qkvT = (u16*)pkb;
    u16*   woT  = qkvT + (size_t)4 * 768 * 256;
    u16*   ff1T = woT + (size_t)4 * 256 * 256;
    u16*   ff2T = ff1T + (size_t)4 * 512 * 256;
    u16*   w2cT = ff2T + (size_t)4 * 512 * 256;
    float* bqkv = (float*)(w2cT + 256 * 128);
    float* pooled = bqkv + 4 * 768;

    // fold 1/sqrt(32) * log2(e) into Wq/bq (softmax in exp2 domain)
    const float qscale = 0.17677669529663687f * 1.4426950408889634f;
    pack_all<<<9372, 256, 0, stream>>>(wq, wk, wv, wo, ff_w1, ff_w2, conv2_w, bq, bk, bv,
                                       qkvT, woT, ff1T, ff2T, w2cT, pe, bqkv, pooled, qscale);

    conv1_im2col_kernel<<<8192, 256, 0, stream>>>(x, conv1_w, conv1_b, A2);
    mfma_gemm128<2><<<dim3(2, 128), 256, 0, stream>>>(A2, 128, w2cT, conv2_b, pe, h, hb,
                                                      nullptr, nullptr, 256, 128);

    for (int l = 0; l < NL_; ++l) {
        const u16* qkvT_l = qkvT + (size_t)l * 768 * 256;
        const u16* woT_l  = woT + (size_t)l * 256 * 256;
        const u16* ff1T_l = ff1T + (size_t)l * 512 * 256;
        const u16* ff2T_l = ff2T + (size_t)l * 256 * 512;

        mfma_gemm128<3><<<dim3(6, 128), 256, 0, stream>>>(hb, 256, qkvT_l, bqkv + l * 768,
                                                          nullptr, nullptr, qbuf, ktl, vtl, 256, 256);
        attn_mfma<<<1024, 256, 0, stream>>>(qbuf, ktl, vtl);
        mfma_gemm_ln<<<512, 256, 0, stream>>>(qbuf, 256, woT_l, bo + l * 256, h,
                                              ln1_g + l * 256, ln1_b + l * 256, h, hb, 256);
        if (l < NL_ - 1) {
            fused_ff<0><<<512, 256, 0, stream>>>(hb, ff1T_l, ff_b1 + l * 512, ff2T_l,
                                                 ff_b2 + l * 256, h, ln2_g + l * 256,
                                                 ln2_b + l * 256, h, hb, nullptr);
        } else {
            fused_ff<1><<<512, 256, 0, stream>>>(hb, ff1T_l, ff_b1 + l * 512, ff2T_l,
                                                 ff_b2 + l * 256, h, ln2_g + l * 256,
                                                 ln2_b + l * 256, h, hb, pooled);
        }
    }

    cls_kernel<<<B_, 256, 0, stream>>>(pooled, cls_w1, cls_b1, cls_w2, cls_b2, (float*)d_out);
}

// Round 11
// 552.710 us; speedup vs baseline: 1.1797x; 1.0830x over previous
//
#include <hip/hip_runtime.h>
#include <math.h>

typedef unsigned short u16;
typedef __attribute__((ext_vector_type(8))) short bf16x8;
typedef __attribute__((ext_vector_type(4))) float f32x4;
typedef __attribute__((ext_vector_type(16))) float f32x16;

#define B_ 16
#define L_ 8192
#define D_ 256
#define H_ 8
#define NL_ 4
#define DFF_ 512
#define S_ 1024
#define L1_ 2048
#define MROWS_ 16384

__device__ __forceinline__ u16 f2bf(float f) {
    unsigned u = __float_as_uint(f);
    unsigned r = (u + 0x7fffu + ((u >> 16) & 1u)) >> 16;   // RNE
    return (u16)r;
}
__device__ __forceinline__ float fexp2(float x) {
    return __builtin_amdgcn_exp2f(x);    // raw v_exp_f32 (2^x)
}
__device__ __forceinline__ unsigned cvtpk(float a, float b) {
    unsigned r;
    asm("v_cvt_pk_bf16_f32 %0, %1, %2" : "=v"(r) : "v"(a), "v"(b));
    return r;
}
__device__ __forceinline__ void pl32swap(unsigned& dst, unsigned& src) {
    asm volatile("v_permlane32_swap_b32 %0, %1" : "+v"(dst), "+v"(src));
}

// ---- async global->LDS (16B per lane) ----
typedef __attribute__((address_space(1))) const void gvoid;
typedef __attribute__((address_space(3))) void lvoid;
__device__ __forceinline__ void gll16(const void* g, void* l) {
    __builtin_amdgcn_global_load_lds((gvoid*)g, (lvoid*)l, 16, 0, 0);
}
__device__ __forceinline__ void stage64(const u16* src, int ld, u16* lds, int tid) {
    gll16(src + (size_t)(tid >> 2) * ld + (tid & 3) * 8, lds + (tid >> 6) * 512);
}

// ---------------- fused conv1 + im2col: x -> A2 bf16 [B*S][128] ----------------
__global__ __launch_bounds__(256) void conv1_im2col_kernel(const float* __restrict__ x,
                                                           const float* __restrict__ w,
                                                           const float* __restrict__ bias,
                                                           u16* __restrict__ A2) {
    int idx = blockIdx.x * 256 + threadIdx.x;   // 2M
    int k = idx & 127, row = idx >> 7;
    int c = k >> 2, j = k & 3;
    int b = row >> 10, s = row & 1023;
    int p = s * 2 - 1 + j;                      // conv1 output position
    float v = 0.f;
    if (p >= 0 && p < L1_) {
        float acc = bias[c];
        int base = p * 4 - 2;
#pragma unroll
        for (int ci = 0; ci < 2; ++ci) {
            const float* xr = x + ((size_t)(b * 2 + ci)) * L_;
            const float* wr = w + (c * 2 + ci) * 8;
#pragma unroll
            for (int jj = 0; jj < 8; ++jj) {
                int pos = base + jj;
                if (pos >= 0 && pos < L_) acc += xr[pos] * wr[jj];
            }
        }
        v = fmaxf(acc, 0.f);
    }
    A2[idx] = f2bf(v);
}

// ---------------- one-shot pack of all weights / PE / biases / zeros ----------------
__global__ __launch_bounds__(256) void pack_all(const float* __restrict__ wq,
                                                const float* __restrict__ wk,
                                                const float* __restrict__ wv,
                                                const float* __restrict__ wo,
                                                const float* __restrict__ ff_w1,
                                                const float* __restrict__ ff_w2,
                                                const float* __restrict__ conv2_w,
                                                const float* __restrict__ bq,
                                                const float* __restrict__ bk,
                                                const float* __restrict__ bv,
                                                u16* __restrict__ qkvT, u16* __restrict__ woT,
                                                u16* __restrict__ ff1T, u16* __restrict__ ff2T,
                                                u16* __restrict__ w2cT,
                                                float* __restrict__ pe, float* __restrict__ bqkv,
                                                float* __restrict__ pooled, float qscale) {
    int id = blockIdx.x * 256 + threadIdx.x;
    if (id < 786432) {                       // qkvT [l][row<768][k]
        int l = id / 196608, j = id % 196608;
        int row = j >> 8, k = j & 255;
        const float* src; float sc = 1.f; int n;
        if (row < 256) { src = wq; n = row; sc = qscale; }
        else if (row < 512) { src = wk; n = row - 256; }
        else { src = wv; n = row - 512; }
        qkvT[id] = f2bf(src[((size_t)l * 256 + k) * 256 + n] * sc);
        return;
    }
    id -= 786432;
    if (id < 262144) {                       // woT
        int l = id >> 16, j = id & 65535;
        int n = j >> 8, k = j & 255;
        woT[id] = f2bf(wo[((size_t)l * 256 + k) * 256 + n]);
        return;
    }
    id -= 262144;
    if (id < 524288) {                       // ff1T: N=512, K=256
        int l = id >> 17, j = id & 131071;
        int n = j >> 8, k = j & 255;
        ff1T[id] = f2bf(ff_w1[((size_t)l * 256 + k) * 512 + n]);
        return;
    }
    id -= 524288;
    if (id < 524288) {                       // ff2T: N=256, K=512
        int l = id >> 17, j = id & 131071;
        int n = j >> 9, k = j & 511;
        ff2T[id] = f2bf(ff_w2[((size_t)l * 512 + k) * 256 + n]);
        return;
    }
    id -= 524288;
    if (id < 32768) { w2cT[id] = f2bf(conv2_w[id]); return; }
    id -= 32768;
    if (id < 262144) {                       // PE table
        int s = id >> 8, d = id & 255;
        int i2 = d & ~1;
        float div = expf((float)i2 * (-9.210340371976184f / 256.f));
        float arg = (float)s * div;
        pe[id] = (d & 1) ? cosf(arg) : sinf(arg);
        return;
    }
    id -= 262144;
    if (id < 3072) {                         // fused qkv bias
        int l = id / 768, n = id % 768;
        const float* src = (n < 256) ? bq : (n < 512) ? bk : bv;
        float sc = (n < 256) ? qscale : 1.f;
        bqkv[id] = src[l * 256 + (n & 255)] * sc;
        return;
    }
    id -= 3072;
    if (id < 4096) pooled[id] = 0.f;
}

// ---------------- MFMA GEMM 128x128, XCD-chunked 1D grid ----------------
// EP=1: bias+relu -> bf16 (ld N). EP=2: relu(bias)+PE -> h fp32 + hb bf16 (conv2).
// EP=3: qkv: col<256 -> Q bf16 ld256; 256-511 -> K tiles [bh][kt][32key][32dim];
//        >=512 -> V^T tiles [bh][kt][32dim][32s].  (linear layouts)
template <int EP, int NT>
__global__ __launch_bounds__(256) void mfma_gemm128(const u16* __restrict__ A, int lda,
                                                    const u16* __restrict__ WT,
                                                    const float* __restrict__ bias,
                                                    const float* __restrict__ pe,
                                                    float* __restrict__ hout,
                                                    u16* __restrict__ outB,
                                                    u16* __restrict__ ktout,
                                                    u16* __restrict__ vtout,
                                                    int N, int K) {
    __shared__ u16 Alds[128 * 32];
    __shared__ u16 Blds[128 * 32];
    int tid = threadIdx.x;
    int lane = tid & 63, w = tid >> 6;
    int lo = lane & 15, hi = lane >> 4;
    // XCD-chunked decode: each XCD owns a contiguous 16-m-tile slab x all NT n-tiles
    int phys = blockIdx.x;
    int cid = phys & 7, idx = phys >> 3;
    int m0 = (cid * 16 + idx / NT) * 128;
    int n0 = (idx % NT) * 128;
    int wm = (w >> 1) * 64, wn = (w & 1) * 64;
    f32x4 acc[4][4];
#pragma unroll
    for (int i = 0; i < 4; ++i)
#pragma unroll
        for (int j = 0; j < 4; ++j) acc[i][j] = (f32x4){0.f, 0.f, 0.f, 0.f};

    for (int k0 = 0; k0 < K; k0 += 32) {
        stage64(A + (size_t)m0 * lda + k0, lda, Alds, tid);
        stage64(A + (size_t)(m0 + 64) * lda + k0, lda, Alds + 2048, tid);
        stage64(WT + (size_t)n0 * K + k0, K, Blds, tid);
        stage64(WT + (size_t)(n0 + 64) * K + k0, K, Blds + 2048, tid);
        __syncthreads();
        bf16x8 af[4], bfr[4];
#pragma unroll
        for (int mf = 0; mf < 4; ++mf) af[mf] = *(bf16x8*)&Alds[(wm + mf * 16 + lo) * 32 + hi * 8];
#pragma unroll
        for (int nf = 0; nf < 4; ++nf) bfr[nf] = *(bf16x8*)&Blds[(wn + nf * 16 + lo) * 32 + hi * 8];
#pragma unroll
        for (int mf = 0; mf < 4; ++mf)
#pragma unroll
            for (int nf = 0; nf < 4; ++nf)
                acc[mf][nf] = __builtin_amdgcn_mfma_f32_16x16x32_bf16(af[mf], bfr[nf], acc[mf][nf], 0, 0, 0);
        __syncthreads();
    }
#pragma unroll
    for (int mf = 0; mf < 4; ++mf)
#pragma unroll
        for (int nf = 0; nf < 4; ++nf) {
            int col = n0 + wn + nf * 16 + lo;
            float bb = bias[col];
            int rowb = m0 + wm + mf * 16 + hi * 4;
            if (EP == 3 && col >= 512) {
                int dc = col - 512;
                int bhh = ((rowb >> 10) << 3) + (dc >> 5);
                int s = rowb & 1023;
                unsigned u0 = (unsigned)f2bf(acc[mf][nf][0] + bb) |
                              ((unsigned)f2bf(acc[mf][nf][1] + bb) << 16);
                unsigned u1 = (unsigned)f2bf(acc[mf][nf][2] + bb) |
                              ((unsigned)f2bf(acc[mf][nf][3] + bb) << 16);
                uint2 val = {u0, u1};
                *(uint2*)(vtout + (((size_t)bhh * 32 + (s >> 5)) * 32 + (dc & 31)) * 32 + (s & 31)) = val;
            } else if (EP == 3 && col >= 256) {
                int kc = col - 256;
                int bhh = ((rowb >> 10) << 3) + (kc >> 5);
                int s = rowb & 1023;
                u16* kt_base = ktout + (((size_t)bhh * 32 + (s >> 5)) * 32) * 32;
#pragma unroll
                for (int r = 0; r < 4; ++r)
                    kt_base[((s & 31) + r) * 32 + (kc & 31)] = f2bf(acc[mf][nf][r] + bb);
            } else {
#pragma unroll
                for (int r = 0; r < 4; ++r) {
                    float v = acc[mf][nf][r] + bb;
                    if (EP == 1 || EP == 2) v = fmaxf(v, 0.f);
                    if (EP == 2) {
                        v += pe[((rowb + r) & 1023) * 256 + col];
                        hout[(size_t)(rowb + r) * 256 + col] = v;
                        outB[(size_t)(rowb + r) * 256 + col] = f2bf(v);
                    } else if (EP == 3) {
                        outB[(size_t)(rowb + r) * 256 + col] = f2bf(v);
                    } else {
                        outB[(size_t)(rowb + r) * N + col] = f2bf(v);
                    }
                }
            }
        }
}

// ---------------- MFMA GEMM 32x256 + fused residual + LayerNorm (+pool on LAST) ----------------
template <int LAST>
__global__ __launch_bounds__(256) void mfma_gemm_ln(const u16* __restrict__ A, int lda,
                                                    const u16* __restrict__ WT,
                                                    const float* __restrict__ bias,
                                                    const float* __restrict__ resid,
                                                    const float* __restrict__ g,
                                                    const float* __restrict__ b2,
                                                    float* __restrict__ hout,
                                                    u16* __restrict__ hbout,
                                                    float* __restrict__ pooled,
                                                    int K) {
    __shared__ u16 Alds[32 * 32];
    __shared__ u16 Blds[256 * 32];
    __shared__ float red1[32][4];
    __shared__ float red2[32][4];
    int tid = threadIdx.x;
    int lane = tid & 63, w = tid >> 6;
    int lo = lane & 15, hi = lane >> 4;
    int phys = blockIdx.x;
    int m0 = ((phys & 7) * 64 + (phys >> 3)) * 32;   // XCD-chunked m-slab
    int wn = w * 64;
    f32x4 acc[2][4];
#pragma unroll
    for (int i = 0; i < 2; ++i)
#pragma unroll
        for (int j = 0; j < 4; ++j) acc[i][j] = (f32x4){0.f, 0.f, 0.f, 0.f};

    for (int k0 = 0; k0 < K; k0 += 32) {
        if (tid < 128)
            gll16(A + (size_t)(m0 + (tid >> 2)) * lda + k0 + (tid & 3) * 8, Alds + (tid >> 6) * 512);
        stage64(WT + (size_t)0 * K + k0, K, Blds, tid);
        stage64(WT + (size_t)64 * K + k0, K, Blds + 2048, tid);
        stage64(WT + (size_t)128 * K + k0, K, Blds + 4096, tid);
        stage64(WT + (size_t)192 * K + k0, K, Blds + 6144, tid);
        __syncthreads();
        bf16x8 af[2], bfr[4];
#pragma unroll
        for (int mf = 0; mf < 2; ++mf) af[mf] = *(bf16x8*)&Alds[(mf * 16 + lo) * 32 + hi * 8];
#pragma unroll
        for (int nf = 0; nf < 4; ++nf) bfr[nf] = *(bf16x8*)&Blds[(wn + nf * 16 + lo) * 32 + hi * 8];
#pragma unroll
        for (int mf = 0; mf < 2; ++mf)
#pragma unroll
            for (int nf = 0; nf < 4; ++nf)
                acc[mf][nf] = __builtin_amdgcn_mfma_f32_16x16x32_bf16(af[mf], bfr[nf], acc[mf][nf], 0, 0, 0);
        __syncthreads();
    }

#pragma unroll
    for (int mf = 0; mf < 2; ++mf)
#pragma unroll
        for (int nf = 0; nf < 4; ++nf) {
            int col = wn + nf * 16 + lo;
            float bb = bias[col];
#pragma unroll
            for (int r = 0; r < 4; ++r) {
                int row = m0 + mf * 16 + hi * 4 + r;
                acc[mf][nf][r] += bb + resid[(size_t)row * 256 + col];
            }
        }
#pragma unroll
    for (int mf = 0; mf < 2; ++mf)
#pragma unroll
        for (int r = 0; r < 4; ++r) {
            float s1 = acc[mf][0][r] + acc[mf][1][r] + acc[mf][2][r] + acc[mf][3][r];
            float s2 = acc[mf][0][r] * acc[mf][0][r] + acc[mf][1][r] * acc[mf][1][r] +
                       acc[mf][2][r] * acc[mf][2][r] + acc[mf][3][r] * acc[mf][3][r];
#pragma unroll
            for (int off = 1; off < 16; off <<= 1) {
                s1 += __shfl_xor(s1, off);
                s2 += __shfl_xor(s2, off);
            }
            if (lo == 0) {
                red1[mf * 16 + hi * 4 + r][w] = s1;
                red2[mf * 16 + hi * 4 + r][w] = s2;
            }
        }
    __syncthreads();
    float colsum[4] = {0.f, 0.f, 0.f, 0.f};
#pragma unroll
    for (int mf = 0; mf < 2; ++mf)
#pragma unroll
        for (int r = 0; r < 4; ++r) {
            int rl = mf * 16 + hi * 4 + r;
            float mean = (red1[rl][0] + red1[rl][1] + red1[rl][2] + red1[rl][3]) * (1.f / 256.f);
            float e2 = (red2[rl][0] + red2[rl][1] + red2[rl][2] + red2[rl][3]) * (1.f / 256.f);
            float rs = rsqrtf(e2 - mean * mean + 1e-5f);
#pragma unroll
            for (int nf = 0; nf < 4; ++nf) {
                int col = wn + nf * 16 + lo;
                float o = (acc[mf][nf][r] - mean) * rs * g[col] + b2[col];
                if (LAST) {
                    colsum[nf] += o;
                } else {
                    hout[(size_t)(m0 + rl) * 256 + col] = o;
                    hbout[(size_t)(m0 + rl) * 256 + col] = f2bf(o);
                }
            }
        }
    if (LAST) {
        int b = m0 >> 10;
#pragma unroll
        for (int nf = 0; nf < 4; ++nf) {
            float cs = colsum[nf];
            cs += __shfl_xor(cs, 16);
            cs += __shfl_xor(cs, 32);
            if (hi == 0) atomicAdd(&pooled[b * 256 + wn + nf * 16 + lo], cs);
        }
    }
}

// ---------------- swapped 32x32 MFMA flash attention (reg prefetch + setprio) ----------------
__global__ __launch_bounds__(256) void attn_mfma(u16* __restrict__ qbuf,
                                                 const u16* __restrict__ ktiles,
                                                 const u16* __restrict__ vtiles) {
    int tid = threadIdx.x;
    int lane = tid & 63, w = tid >> 6;
    int q = lane & 31, h = lane >> 5;
    int phys = blockIdx.x;
    int bid = (phys & 7) * 128 + (phys >> 3);   // XCD-contiguous: 16 (b,h) per XCD
    int qt = bid & 7, hh = (bid >> 3) & 7, bb = bid >> 6;
    int q0 = qt * 128 + w * 32;
    size_t rowbase = (size_t)bb * S_;

    const u16* qrow = qbuf + (rowbase + q0 + q) * 256 + hh * 32;
    bf16x8 qf0 = *(const bf16x8*)(qrow + h * 8);
    bf16x8 qf1 = *(const bf16x8*)(qrow + 16 + h * 8);

    const u16* kb = ktiles + (size_t)(bb * 8 + hh) * 32768 + q * 32 + h * 8;
    const u16* vb = vtiles + (size_t)(bb * 8 + hh) * 32768 + q * 32 + h * 8;

    f32x16 O = {0.f, 0.f, 0.f, 0.f, 0.f, 0.f, 0.f, 0.f, 0.f, 0.f, 0.f, 0.f, 0.f, 0.f, 0.f, 0.f};
    float l = 0.f;

#define LOADT(d0, d1, d2, d3, t)                         \
    {                                                    \
        const u16* kr = kb + (t) * 1024;                 \
        d0 = *(const bf16x8*)kr;                         \
        d1 = *(const bf16x8*)(kr + 16);                  \
        const u16* vr = vb + (t) * 1024;                 \
        d2 = *(const bf16x8*)vr;                         \
        d3 = *(const bf16x8*)(vr + 16);                  \
    }

#define TILE_BODY(kf0_, kf1_, vf0_, vf1_)                                               \
    {                                                                                   \
        f32x16 S = {0.f, 0.f, 0.f, 0.f, 0.f, 0.f, 0.f, 0.f,                             \
                    0.f, 0.f, 0.f, 0.f, 0.f, 0.f, 0.f, 0.f};                            \
        __builtin_amdgcn_s_setprio(1);                                                  \
        S = __builtin_amdgcn_mfma_f32_32x32x16_bf16(kf0_, qf0, S, 0, 0, 0);             \
        S = __builtin_amdgcn_mfma_f32_32x32x16_bf16(kf1_, qf1, S, 0, 0, 0);             \
        __builtin_amdgcn_s_setprio(0);                                                  \
        _Pragma("unroll") for (int i = 0; i < 16; ++i) S[i] = fexp2(S[i]);              \
        float t0 = (S[0] + S[1]) + (S[2] + S[3]);                                       \
        float t1 = (S[4] + S[5]) + (S[6] + S[7]);                                       \
        float t2 = (S[8] + S[9]) + (S[10] + S[11]);                                     \
        float t3 = (S[12] + S[13]) + (S[14] + S[15]);                                   \
        float ls = (t0 + t1) + (t2 + t3);                                               \
        unsigned ua = __float_as_uint(ls), ub = ua;                                     \
        pl32swap(ua, ub);                                                               \
        l += __uint_as_float(ua) + __uint_as_float(ub);                                 \
        unsigned pk[8];                                                                 \
        _Pragma("unroll") for (int i = 0; i < 8; ++i) pk[i] = cvtpk(S[2 * i], S[2 * i + 1]); \
        pl32swap(pk[2], pk[0]);                                                         \
        pl32swap(pk[3], pk[1]);                                                         \
        pl32swap(pk[6], pk[4]);                                                         \
        pl32swap(pk[7], pk[5]);                                                         \
        uint4 t4 = {pk[0], pk[1], pk[2], pk[3]};                                        \
        uint4 t5 = {pk[4], pk[5], pk[6], pk[7]};                                        \
        bf16x8 pf0 = *(bf16x8*)&t4;                                                     \
        bf16x8 pf1 = *(bf16x8*)&t5;                                                     \
        __builtin_amdgcn_s_setprio(1);                                                  \
        O = __builtin_amdgcn_mfma_f32_32x32x16_bf16(vf0_, pf0, O, 0, 0, 0);             \
        O = __builtin_amdgcn_mfma_f32_32x32x16_bf16(vf1_, pf1, O, 0, 0, 0);             \
        __builtin_amdgcn_s_setprio(0);                                                  \
    }

    bf16x8 ka0, ka1, va0, va1, kb0, kb1, vb0, vb1;
    LOADT(ka0, ka1, va0, va1, 0);
    LOADT(kb0, kb1, vb0, vb1, 1);
    for (int kt = 0; kt < 32; kt += 2) {
        bf16x8 kc0 = ka0, kc1 = ka1, vc0 = va0, vc1 = va1;
        if (kt + 2 < 32) LOADT(kc0, kc1, vc0, vc1, kt + 2);
        TILE_BODY(ka0, ka1, va0, va1);
        bf16x8 kd0 = kb0, kd1 = kb1, vd0 = vb0, vd1 = vb1;
        if (kt + 3 < 32) LOADT(kd0, kd1, vd0, vd1, kt + 3);
        TILE_BODY(kb0, kb1, vb0, vb1);
        ka0 = kc0; ka1 = kc1; va0 = vc0; va1 = vc1;
        kb0 = kd0; kb1 = kd1; vb0 = vd0; vb1 = vd1;
    }
#undef LOADT
#undef TILE_BODY

    float inv = 1.f / l;
    u16* orow = qbuf + (rowbase + q0 + q) * 256 + hh * 32;
#pragma unroll
    for (int gg = 0; gg < 4; ++gg) {
        unsigned u0 = cvtpk(O[4 * gg] * inv, O[4 * gg + 1] * inv);
        unsigned u1 = cvtpk(O[4 * gg + 2] * inv, O[4 * gg + 3] * inv);
        uint2 val = {u0, u1};
        *(uint2*)(orow + gg * 8 + h * 4) = val;
    }
}

// ---------------- classifier from pooled sums ----------------
__global__ __launch_bounds__(256) void cls_kernel(const float* __restrict__ pooled,
                                                  const float* __restrict__ w1,
                                                  const float* __restrict__ b1,
                                                  const float* __restrict__ w2,
                                                  const float* __restrict__ b2,
                                                  float* __restrict__ out) {
    int b = blockIdx.x;
    int d = threadIdx.x;
    __shared__ float pl[256];
    __shared__ float hid[128];
    pl[d] = pooled[b * 256 + d] * (1.f / 1024.f);
    __syncthreads();
    if (d < 128) {
        float a = b1[d];
        for (int k = 0; k < 256; ++k) a += pl[k] * w1[k * 128 + d];
        hid[d] = fmaxf(a, 0.f);
    }
    __syncthreads();
    if (d == 0) {
        float a = b2[0];
        for (int k = 0; k < 128; ++k) a += hid[k] * w2[k];
        out[b] = 1.f / (1.f + expf(-a));
    }
}

extern "C" void kernel_launch(void* const* d_in, const int* in_sizes, int n_in,
                              void* d_out, int out_size, void* d_ws, size_t ws_size,
                              hipStream_t stream) {
    const float* x       = (const float*)d_in[0];
    const float* conv1_w = (const float*)d_in[1];
    const float* conv1_b = (const float*)d_in[2];
    const float* conv2_w = (const float*)d_in[3];
    const float* conv2_b = (const float*)d_in[4];
    const float* wq      = (const float*)d_in[5];
    const float* bq      = (const float*)d_in[6];
    const float* wk      = (const float*)d_in[7];
    const float* bk      = (const float*)d_in[8];
    const float* wv      = (const float*)d_in[9];
    const float* bv      = (const float*)d_in[10];
    const float* wo      = (const float*)d_in[11];
    const float* bo      = (const float*)d_in[12];
    const float* ln1_g   = (const float*)d_in[13];
    const float* ln1_b   = (const float*)d_in[14];
    const float* ff_w1   = (const float*)d_in[15];
    const float* ff_b1   = (const float*)d_in[16];
    const float* ff_w2   = (const float*)d_in[17];
    const float* ff_b2   = (const float*)d_in[18];
    const float* ln2_g   = (const float*)d_in[19];
    const float* ln2_b   = (const float*)d_in[20];
    const float* cls_w1  = (const float*)d_in[21];
    const float* cls_b1  = (const float*)d_in[22];
    const float* cls_w2  = (const float*)d_in[23];
    const float* cls_b2  = (const float*)d_in[24];

    char* wsb = (char*)d_ws;
    float* h    = (float*)wsb;
    u16*   hb   = (u16*)(wsb + ((size_t)16 << 20));
    u16*   qbuf = (u16*)(wsb + ((size_t)24 << 20));
    u16*   ktl  = (u16*)(wsb + ((size_t)32 << 20));
    u16*   vtl  = (u16*)(wsb + ((size_t)40 << 20));
    u16*   ffh  = (u16*)(wsb + ((size_t)32 << 20));   // overlays ktl+vtl (dead after attn)
    u16*   A2   = (u16*)(wsb + ((size_t)32 << 20));   // conv scratch (dead after conv2 gemm)
    float* pe   = (float*)(wsb + ((size_t)48 << 20));
    char*  pkb  = wsb + ((size_t)49 << 20);
    u16*   qkvT = (u16*)pkb;
    u16*   woT  = qkvT + (size_t)4 * 768 * 256;
    u16*   ff1T = woT + (size_t)4 * 256 * 256;
    u16*   ff2T = ff1T + (size_t)4 * 512 * 256;
    u16*   w2cT = ff2T + (size_t)4 * 512 * 256;
    float* bqkv = (float*)(w2cT + 256 * 128);
    float* pooled = bqkv + 4 * 768;

    // fold 1/sqrt(32) * log2(e) into Wq/bq (softmax in exp2 domain)
    const float qscale = 0.17677669529663687f * 1.4426950408889634f;
    pack_all<<<9372, 256, 0, stream>>>(wq, wk, wv, wo, ff_w1, ff_w2, conv2_w, bq, bk, bv,
                                       qkvT, woT, ff1T, ff2T, w2cT, pe, bqkv, pooled, qscale);

    conv1_im2col_kernel<<<8192, 256, 0, stream>>>(x, conv1_w, conv1_b, A2);
    mfma_gemm128<2, 2><<<256, 256, 0, stream>>>(A2, 128, w2cT, conv2_b, pe, h, hb,
                                                nullptr, nullptr, 256, 128);

    for (int l = 0; l < NL_; ++l) {
        const u16* qkvT_l = qkvT + (size_t)l * 768 * 256;
        const u16* woT_l  = woT + (size_t)l * 256 * 256;
        const u16* ff1T_l = ff1T + (size_t)l * 512 * 256;
        const u16* ff2T_l = ff2T + (size_t)l * 256 * 512;

        mfma_gemm128<3, 6><<<768, 256, 0, stream>>>(hb, 256, qkvT_l, bqkv + l * 768,
                                                    nullptr, nullptr, qbuf, ktl, vtl, 256, 256);
        attn_mfma<<<1024, 256, 0, stream>>>(qbuf, ktl, vtl);
        mfma_gemm_ln<0><<<512, 256, 0, stream>>>(qbuf, 256, woT_l, bo + l * 256, h,
                                                 ln1_g + l * 256, ln1_b + l * 256, h, hb, nullptr, 256);
        mfma_gemm128<1, 4><<<512, 256, 0, stream>>>(hb, 256, ff1T_l, ff_b1 + l * 512,
                                                    nullptr, nullptr, ffh, nullptr, nullptr, 512, 256);
        if (l < NL_ - 1) {
            mfma_gemm_ln<0><<<512, 256, 0, stream>>>(ffh, 512, ff2T_l, ff_b2 + l * 256, h,
                                                     ln2_g + l * 256, ln2_b + l * 256, h, hb, nullptr, 512);
        } else {
            mfma_gemm_ln<1><<<512, 256, 0, stream>>>(ffh, 512, ff2T_l, ff_b2 + l * 256, h,
                                                     ln2_g + l * 256, ln2_b + l * 256, h, hb, pooled, 512);
        }
    }

    cls_kernel<<<B_, 256, 0, stream>>>(pooled, cls_w1, cls_b1, cls_w2, cls_b2, (float*)d_out);
}

// Round 12
// 529.317 us; speedup vs baseline: 1.2318x; 1.0442x over previous
//
#include <hip/hip_runtime.h>
#include <math.h>

typedef unsigned short u16;
typedef __attribute__((ext_vector_type(8))) short bf16x8;
typedef __attribute__((ext_vector_type(4))) float f32x4;
typedef __attribute__((ext_vector_type(16))) float f32x16;

#define B_ 16
#define L_ 8192
#define D_ 256
#define H_ 8
#define NL_ 4
#define DFF_ 512
#define S_ 1024
#define L1_ 2048
#define MROWS_ 16384

__device__ __forceinline__ u16 f2bf(float f) {
    unsigned u = __float_as_uint(f);
    unsigned r = (u + 0x7fffu + ((u >> 16) & 1u)) >> 16;   // RNE
    return (u16)r;
}
__device__ __forceinline__ float fexp2(float x) {
    return __builtin_amdgcn_exp2f(x);    // raw v_exp_f32 (2^x)
}
__device__ __forceinline__ unsigned cvtpk(float a, float b) {
    unsigned r;
    asm("v_cvt_pk_bf16_f32 %0, %1, %2" : "=v"(r) : "v"(a), "v"(b));
    return r;
}
__device__ __forceinline__ void pl32swap(unsigned& dst, unsigned& src) {
    asm volatile("v_permlane32_swap_b32 %0, %1" : "+v"(dst), "+v"(src));
}

// ---- async global->LDS (16B per lane) ----
typedef __attribute__((address_space(1))) const void gvoid;
typedef __attribute__((address_space(3))) void lvoid;
__device__ __forceinline__ void gll16(const void* g, void* l) {
    __builtin_amdgcn_global_load_lds((gvoid*)g, (lvoid*)l, 16, 0, 0);
}
__device__ __forceinline__ void stage64(const u16* src, int ld, u16* lds, int tid) {
    gll16(src + (size_t)(tid >> 2) * ld + (tid & 3) * 8, lds + (tid >> 6) * 512);
}

// ---------------- fused conv1 + im2col: x -> A2 bf16 [B*S][128] ----------------
__global__ __launch_bounds__(256) void conv1_im2col_kernel(const float* __restrict__ x,
                                                           const float* __restrict__ w,
                                                           const float* __restrict__ bias,
                                                           u16* __restrict__ A2) {
    int idx = blockIdx.x * 256 + threadIdx.x;   // 2M
    int k = idx & 127, row = idx >> 7;
    int c = k >> 2, j = k & 3;
    int b = row >> 10, s = row & 1023;
    int p = s * 2 - 1 + j;                      // conv1 output position
    float v = 0.f;
    if (p >= 0 && p < L1_) {
        float acc = bias[c];
        int base = p * 4 - 2;
#pragma unroll
        for (int ci = 0; ci < 2; ++ci) {
            const float* xr = x + ((size_t)(b * 2 + ci)) * L_;
            const float* wr = w + (c * 2 + ci) * 8;
#pragma unroll
            for (int jj = 0; jj < 8; ++jj) {
                int pos = base + jj;
                if (pos >= 0 && pos < L_) acc += xr[pos] * wr[jj];
            }
        }
        v = fmaxf(acc, 0.f);
    }
    A2[idx] = f2bf(v);
}

// ---------------- one-shot pack of all weights / PE / biases / zeros ----------------
__global__ __launch_bounds__(256) void pack_all(const float* __restrict__ wq,
                                                const float* __restrict__ wk,
                                                const float* __restrict__ wv,
                                                const float* __restrict__ wo,
                                                const float* __restrict__ ff_w1,
                                                const float* __restrict__ ff_w2,
                                                const float* __restrict__ conv2_w,
                                                const float* __restrict__ bq,
                                                const float* __restrict__ bk,
                                                const float* __restrict__ bv,
                                                u16* __restrict__ qkvT, u16* __restrict__ woT,
                                                u16* __restrict__ ff1T, u16* __restrict__ ff2T,
                                                u16* __restrict__ w2cT,
                                                float* __restrict__ pe, float* __restrict__ bqkv,
                                                float* __restrict__ pooled, float qscale) {
    int id = blockIdx.x * 256 + threadIdx.x;
    if (id < 786432) {                       // qkvT [l][row<768][k]
        int l = id / 196608, j = id % 196608;
        int row = j >> 8, k = j & 255;
        const float* src; float sc = 1.f; int n;
        if (row < 256) { src = wq; n = row; sc = qscale; }
        else if (row < 512) { src = wk; n = row - 256; }
        else { src = wv; n = row - 512; }
        qkvT[id] = f2bf(src[((size_t)l * 256 + k) * 256 + n] * sc);
        return;
    }
    id -= 786432;
    if (id < 262144) {                       // woT
        int l = id >> 16, j = id & 65535;
        int n = j >> 8, k = j & 255;
        woT[id] = f2bf(wo[((size_t)l * 256 + k) * 256 + n]);
        return;
    }
    id -= 262144;
    if (id < 524288) {                       // ff1T: N=512, K=256
        int l = id >> 17, j = id & 131071;
        int n = j >> 8, k = j & 255;
        ff1T[id] = f2bf(ff_w1[((size_t)l * 256 + k) * 512 + n]);
        return;
    }
    id -= 524288;
    if (id < 524288) {                       // ff2T: N=256, K=512
        int l = id >> 17, j = id & 131071;
        int n = j >> 9, k = j & 511;
        ff2T[id] = f2bf(ff_w2[((size_t)l * 512 + k) * 256 + n]);
        return;
    }
    id -= 524288;
    if (id < 32768) { w2cT[id] = f2bf(conv2_w[id]); return; }
    id -= 32768;
    if (id < 262144) {                       // PE table
        int s = id >> 8, d = id & 255;
        int i2 = d & ~1;
        float div = expf((float)i2 * (-9.210340371976184f / 256.f));
        float arg = (float)s * div;
        pe[id] = (d & 1) ? cosf(arg) : sinf(arg);
        return;
    }
    id -= 262144;
    if (id < 3072) {                         // fused qkv bias
        int l = id / 768, n = id % 768;
        const float* src = (n < 256) ? bq : (n < 512) ? bk : bv;
        float sc = (n < 256) ? qscale : 1.f;
        bqkv[id] = src[l * 256 + (n & 255)] * sc;
        return;
    }
    id -= 3072;
    if (id < 4096) pooled[id] = 0.f;
}

// ---------------- MFMA GEMM 128x128, XCD-chunked 1D grid ----------------
// EP=2: relu(bias)+PE -> h fp32 + hb bf16 (conv2).
// EP=3: qkv: col<256 -> Q bf16 ld256; 256-511 -> K tiles [bh][kt][32key][32dim];
//        >=512 -> V^T tiles [bh][kt][32dim][32s].  (linear layouts)
template <int EP, int NT>
__global__ __launch_bounds__(256) void mfma_gemm128(const u16* __restrict__ A, int lda,
                                                    const u16* __restrict__ WT,
                                                    const float* __restrict__ bias,
                                                    const float* __restrict__ pe,
                                                    float* __restrict__ hout,
                                                    u16* __restrict__ outB,
                                                    u16* __restrict__ ktout,
                                                    u16* __restrict__ vtout,
                                                    int N, int K) {
    __shared__ u16 Alds[128 * 32];
    __shared__ u16 Blds[128 * 32];
    int tid = threadIdx.x;
    int lane = tid & 63, w = tid >> 6;
    int lo = lane & 15, hi = lane >> 4;
    int phys = blockIdx.x;
    int cid = phys & 7, idx = phys >> 3;
    int m0 = (cid * 16 + idx / NT) * 128;
    int n0 = (idx % NT) * 128;
    int wm = (w >> 1) * 64, wn = (w & 1) * 64;
    f32x4 acc[4][4];
#pragma unroll
    for (int i = 0; i < 4; ++i)
#pragma unroll
        for (int j = 0; j < 4; ++j) acc[i][j] = (f32x4){0.f, 0.f, 0.f, 0.f};

    for (int k0 = 0; k0 < K; k0 += 32) {
        stage64(A + (size_t)m0 * lda + k0, lda, Alds, tid);
        stage64(A + (size_t)(m0 + 64) * lda + k0, lda, Alds + 2048, tid);
        stage64(WT + (size_t)n0 * K + k0, K, Blds, tid);
        stage64(WT + (size_t)(n0 + 64) * K + k0, K, Blds + 2048, tid);
        __syncthreads();
        bf16x8 af[4], bfr[4];
#pragma unroll
        for (int mf = 0; mf < 4; ++mf) af[mf] = *(bf16x8*)&Alds[(wm + mf * 16 + lo) * 32 + hi * 8];
#pragma unroll
        for (int nf = 0; nf < 4; ++nf) bfr[nf] = *(bf16x8*)&Blds[(wn + nf * 16 + lo) * 32 + hi * 8];
#pragma unroll
        for (int mf = 0; mf < 4; ++mf)
#pragma unroll
            for (int nf = 0; nf < 4; ++nf)
                acc[mf][nf] = __builtin_amdgcn_mfma_f32_16x16x32_bf16(af[mf], bfr[nf], acc[mf][nf], 0, 0, 0);
        __syncthreads();
    }
#pragma unroll
    for (int mf = 0; mf < 4; ++mf)
#pragma unroll
        for (int nf = 0; nf < 4; ++nf) {
            int col = n0 + wn + nf * 16 + lo;
            float bb = bias[col];
            int rowb = m0 + wm + mf * 16 + hi * 4;
            if (EP == 3 && col >= 512) {
                int dc = col - 512;
                int bhh = ((rowb >> 10) << 3) + (dc >> 5);
                int s = rowb & 1023;
                unsigned u0 = (unsigned)f2bf(acc[mf][nf][0] + bb) |
                              ((unsigned)f2bf(acc[mf][nf][1] + bb) << 16);
                unsigned u1 = (unsigned)f2bf(acc[mf][nf][2] + bb) |
                              ((unsigned)f2bf(acc[mf][nf][3] + bb) << 16);
                uint2 val = {u0, u1};
                *(uint2*)(vtout + (((size_t)bhh * 32 + (s >> 5)) * 32 + (dc & 31)) * 32 + (s & 31)) = val;
            } else if (EP == 3 && col >= 256) {
                int kc = col - 256;
                int bhh = ((rowb >> 10) << 3) + (kc >> 5);
                int s = rowb & 1023;
                u16* kt_base = ktout + (((size_t)bhh * 32 + (s >> 5)) * 32) * 32;
#pragma unroll
                for (int r = 0; r < 4; ++r)
                    kt_base[((s & 31) + r) * 32 + (kc & 31)] = f2bf(acc[mf][nf][r] + bb);
            } else {
#pragma unroll
                for (int r = 0; r < 4; ++r) {
                    float v = acc[mf][nf][r] + bb;
                    if (EP == 2) v = fmaxf(v, 0.f);
                    if (EP == 2) {
                        v += pe[((rowb + r) & 1023) * 256 + col];
                        hout[(size_t)(rowb + r) * 256 + col] = v;
                        outB[(size_t)(rowb + r) * 256 + col] = f2bf(v);
                    } else {
                        outB[(size_t)(rowb + r) * 256 + col] = f2bf(v);
                    }
                }
            }
        }
}

// ---------------- MFMA GEMM 32x256 + fused residual + LayerNorm (wo path) ----------------
__global__ __launch_bounds__(256) void mfma_gemm_ln(const u16* __restrict__ A, int lda,
                                                    const u16* __restrict__ WT,
                                                    const float* __restrict__ bias,
                                                    const float* __restrict__ resid,
                                                    const float* __restrict__ g,
                                                    const float* __restrict__ b2,
                                                    float* __restrict__ hout,
                                                    u16* __restrict__ hbout,
                                                    int K) {
    __shared__ u16 Alds[32 * 32];
    __shared__ u16 Blds[256 * 32];
    __shared__ float red1[32][4];
    __shared__ float red2[32][4];
    int tid = threadIdx.x;
    int lane = tid & 63, w = tid >> 6;
    int lo = lane & 15, hi = lane >> 4;
    int phys = blockIdx.x;
    int m0 = ((phys & 7) * 64 + (phys >> 3)) * 32;   // XCD-chunked m-slab
    int wn = w * 64;
    f32x4 acc[2][4];
#pragma unroll
    for (int i = 0; i < 2; ++i)
#pragma unroll
        for (int j = 0; j < 4; ++j) acc[i][j] = (f32x4){0.f, 0.f, 0.f, 0.f};

    for (int k0 = 0; k0 < K; k0 += 32) {
        if (tid < 128)
            gll16(A + (size_t)(m0 + (tid >> 2)) * lda + k0 + (tid & 3) * 8, Alds + (tid >> 6) * 512);
        stage64(WT + (size_t)0 * K + k0, K, Blds, tid);
        stage64(WT + (size_t)64 * K + k0, K, Blds + 2048, tid);
        stage64(WT + (size_t)128 * K + k0, K, Blds + 4096, tid);
        stage64(WT + (size_t)192 * K + k0, K, Blds + 6144, tid);
        __syncthreads();
        bf16x8 af[2], bfr[4];
#pragma unroll
        for (int mf = 0; mf < 2; ++mf) af[mf] = *(bf16x8*)&Alds[(mf * 16 + lo) * 32 + hi * 8];
#pragma unroll
        for (int nf = 0; nf < 4; ++nf) bfr[nf] = *(bf16x8*)&Blds[(wn + nf * 16 + lo) * 32 + hi * 8];
#pragma unroll
        for (int mf = 0; mf < 2; ++mf)
#pragma unroll
            for (int nf = 0; nf < 4; ++nf)
                acc[mf][nf] = __builtin_amdgcn_mfma_f32_16x16x32_bf16(af[mf], bfr[nf], acc[mf][nf], 0, 0, 0);
        __syncthreads();
    }

#pragma unroll
    for (int mf = 0; mf < 2; ++mf)
#pragma unroll
        for (int nf = 0; nf < 4; ++nf) {
            int col = wn + nf * 16 + lo;
            float bb = bias[col];
#pragma unroll
            for (int r = 0; r < 4; ++r) {
                int row = m0 + mf * 16 + hi * 4 + r;
                acc[mf][nf][r] += bb + resid[(size_t)row * 256 + col];
            }
        }
#pragma unroll
    for (int mf = 0; mf < 2; ++mf)
#pragma unroll
        for (int r = 0; r < 4; ++r) {
            float s1 = acc[mf][0][r] + acc[mf][1][r] + acc[mf][2][r] + acc[mf][3][r];
            float s2 = acc[mf][0][r] * acc[mf][0][r] + acc[mf][1][r] * acc[mf][1][r] +
                       acc[mf][2][r] * acc[mf][2][r] + acc[mf][3][r] * acc[mf][3][r];
#pragma unroll
            for (int off = 1; off < 16; off <<= 1) {
                s1 += __shfl_xor(s1, off);
                s2 += __shfl_xor(s2, off);
            }
            if (lo == 0) {
                red1[mf * 16 + hi * 4 + r][w] = s1;
                red2[mf * 16 + hi * 4 + r][w] = s2;
            }
        }
    __syncthreads();
#pragma unroll
    for (int mf = 0; mf < 2; ++mf)
#pragma unroll
        for (int r = 0; r < 4; ++r) {
            int rl = mf * 16 + hi * 4 + r;
            float mean = (red1[rl][0] + red1[rl][1] + red1[rl][2] + red1[rl][3]) * (1.f / 256.f);
            float e2 = (red2[rl][0] + red2[rl][1] + red2[rl][2] + red2[rl][3]) * (1.f / 256.f);
            float rs = rsqrtf(e2 - mean * mean + 1e-5f);
#pragma unroll
            for (int nf = 0; nf < 4; ++nf) {
                int col = wn + nf * 16 + lo;
                float o = (acc[mf][nf][r] - mean) * rs * g[col] + b2[col];
                hout[(size_t)(m0 + rl) * 256 + col] = o;
                hbout[(size_t)(m0 + rl) * 256 + col] = f2bf(o);
            }
        }
}

// ---------------- fused FF: relu(A@W1+b1)@W2 + b2 + resid -> LN (+pool on LAST) ----------------
// All operands LDS-staged (coalesced stage64). Hidden kept in LDS [32 m][512 k] with
// XOR swizzle (u16 idx ^= (m&7)<<3) to break the 1KB-row-stride bank conflict on A-reads.
template <int LAST>
__global__ __launch_bounds__(256) void fused_ff(const u16* __restrict__ A,
                                                const u16* __restrict__ W1T,
                                                const float* __restrict__ b1,
                                                const u16* __restrict__ W2T,
                                                const float* __restrict__ b2,
                                                const float* __restrict__ resid,
                                                const float* __restrict__ g,
                                                const float* __restrict__ bln,
                                                float* __restrict__ hout,
                                                u16* __restrict__ hbout,
                                                float* __restrict__ pooled) {
    __shared__ u16 Blds[512 * 32];       // 32KB: W1 panel [512 n][32 k] (phase2: W2 [256][32])
    __shared__ u16 Alds[32 * 32];        // 2KB
    __shared__ u16 hid[32 * 512];        // 32KB, swizzled
    __shared__ float red1[32][4];
    __shared__ float red2[32][4];
    int tid = threadIdx.x;
    int lane = tid & 63, w = tid >> 6;
    int lo = lane & 15, hi = lane >> 4;
    int phys = blockIdx.x;
    int m0 = ((phys & 7) * 64 + (phys >> 3)) * 32;   // XCD-chunked m-slab

    // ---- phase 1: hid = relu(A @ W1 + b1); wave w owns hidden cols w*128..+127
    {
        int wn = w * 128;
        f32x4 acc1[2][8];
#pragma unroll
        for (int i = 0; i < 2; ++i)
#pragma unroll
            for (int j = 0; j < 8; ++j) acc1[i][j] = (f32x4){0.f, 0.f, 0.f, 0.f};
        for (int k0 = 0; k0 < 256; k0 += 32) {
            if (tid < 128)
                gll16(A + (size_t)(m0 + (tid >> 2)) * 256 + k0 + (tid & 3) * 8, Alds + (tid >> 6) * 512);
#pragma unroll
            for (int rr = 0; rr < 8; ++rr)
                stage64(W1T + (size_t)(rr * 64) * 256 + k0, 256, Blds + rr * 2048, tid);
            __syncthreads();
            bf16x8 af[2], bfr[8];
#pragma unroll
            for (int mf = 0; mf < 2; ++mf) af[mf] = *(bf16x8*)&Alds[(mf * 16 + lo) * 32 + hi * 8];
#pragma unroll
            for (int nf = 0; nf < 8; ++nf) bfr[nf] = *(bf16x8*)&Blds[(wn + nf * 16 + lo) * 32 + hi * 8];
#pragma unroll
            for (int mf = 0; mf < 2; ++mf)
#pragma unroll
                for (int nf = 0; nf < 8; ++nf)
                    acc1[mf][nf] = __builtin_amdgcn_mfma_f32_16x16x32_bf16(af[mf], bfr[nf], acc1[mf][nf], 0, 0, 0);
            __syncthreads();
        }
        // write hidden to swizzled LDS
#pragma unroll
        for (int mf = 0; mf < 2; ++mf)
#pragma unroll
            for (int nf = 0; nf < 8; ++nf) {
                int col = wn + nf * 16 + lo;
                float bb = b1[col];
#pragma unroll
                for (int r = 0; r < 4; ++r) {
                    int m = mf * 16 + hi * 4 + r;
                    hid[(m * 512 + col) ^ ((m & 7) << 3)] = f2bf(fmaxf(acc1[mf][nf][r] + bb, 0.f));
                }
            }
    }
    __syncthreads();

    // ---- phase 2: out = hid @ W2 + b2 + resid -> LN; wave w owns out cols w*64..+63
    int wn = w * 64;
    f32x4 acc[2][4];
#pragma unroll
    for (int i = 0; i < 2; ++i)
#pragma unroll
        for (int j = 0; j < 4; ++j) acc[i][j] = (f32x4){0.f, 0.f, 0.f, 0.f};
    for (int k0 = 0; k0 < 512; k0 += 32) {
#pragma unroll
        for (int rr = 0; rr < 4; ++rr)
            stage64(W2T + (size_t)(rr * 64) * 512 + k0, 512, Blds + rr * 2048, tid);
        __syncthreads();
        bf16x8 af[2], bfr[4];
#pragma unroll
        for (int mf = 0; mf < 2; ++mf) {
            int m = mf * 16 + lo;
            af[mf] = *(bf16x8*)&hid[(m * 512 + k0 + hi * 8) ^ ((m & 7) << 3)];
        }
#pragma unroll
        for (int nf = 0; nf < 4; ++nf) bfr[nf] = *(bf16x8*)&Blds[(wn + nf * 16 + lo) * 32 + hi * 8];
#pragma unroll
        for (int mf = 0; mf < 2; ++mf)
#pragma unroll
            for (int nf = 0; nf < 4; ++nf)
                acc[mf][nf] = __builtin_amdgcn_mfma_f32_16x16x32_bf16(af[mf], bfr[nf], acc[mf][nf], 0, 0, 0);
        __syncthreads();
    }

#pragma unroll
    for (int mf = 0; mf < 2; ++mf)
#pragma unroll
        for (int nf = 0; nf < 4; ++nf) {
            int col = wn + nf * 16 + lo;
            float bb = b2[col];
#pragma unroll
            for (int r = 0; r < 4; ++r) {
                int row = m0 + mf * 16 + hi * 4 + r;
                acc[mf][nf][r] += bb + resid[(size_t)row * 256 + col];
            }
        }
#pragma unroll
    for (int mf = 0; mf < 2; ++mf)
#pragma unroll
        for (int r = 0; r < 4; ++r) {
            float s1 = acc[mf][0][r] + acc[mf][1][r] + acc[mf][2][r] + acc[mf][3][r];
            float s2 = acc[mf][0][r] * acc[mf][0][r] + acc[mf][1][r] * acc[mf][1][r] +
                       acc[mf][2][r] * acc[mf][2][r] + acc[mf][3][r] * acc[mf][3][r];
#pragma unroll
            for (int off = 1; off < 16; off <<= 1) {
                s1 += __shfl_xor(s1, off);
                s2 += __shfl_xor(s2, off);
            }
            if (lo == 0) {
                red1[mf * 16 + hi * 4 + r][w] = s1;
                red2[mf * 16 + hi * 4 + r][w] = s2;
            }
        }
    __syncthreads();
    float colsum[4] = {0.f, 0.f, 0.f, 0.f};
#pragma unroll
    for (int mf = 0; mf < 2; ++mf)
#pragma unroll
        for (int r = 0; r < 4; ++r) {
            int rl = mf * 16 + hi * 4 + r;
            float mean = (red1[rl][0] + red1[rl][1] + red1[rl][2] + red1[rl][3]) * (1.f / 256.f);
            float e2 = (red2[rl][0] + red2[rl][1] + red2[rl][2] + red2[rl][3]) * (1.f / 256.f);
            float rs = rsqrtf(e2 - mean * mean + 1e-5f);
#pragma unroll
            for (int nf = 0; nf < 4; ++nf) {
                int col = wn + nf * 16 + lo;
                float o = (acc[mf][nf][r] - mean) * rs * g[col] + bln[col];
                if (LAST) {
                    colsum[nf] += o;
                } else {
                    hout[(size_t)(m0 + rl) * 256 + col] = o;
                    hbout[(size_t)(m0 + rl) * 256 + col] = f2bf(o);
                }
            }
        }
    if (LAST) {
        int b = m0 >> 10;
#pragma unroll
        for (int nf = 0; nf < 4; ++nf) {
            float cs = colsum[nf];
            cs += __shfl_xor(cs, 16);
            cs += __shfl_xor(cs, 32);
            if (hi == 0) atomicAdd(&pooled[b * 256 + wn + nf * 16 + lo], cs);
        }
    }
}

// ---------------- swapped 32x32 MFMA flash attention (reg prefetch + setprio) ----------------
__global__ __launch_bounds__(256) void attn_mfma(u16* __restrict__ qbuf,
                                                 const u16* __restrict__ ktiles,
                                                 const u16* __restrict__ vtiles) {
    int tid = threadIdx.x;
    int lane = tid & 63, w = tid >> 6;
    int q = lane & 31, h = lane >> 5;
    int phys = blockIdx.x;
    int bid = (phys & 7) * 128 + (phys >> 3);   // XCD-contiguous: 16 (b,h) per XCD
    int qt = bid & 7, hh = (bid >> 3) & 7, bb = bid >> 6;
    int q0 = qt * 128 + w * 32;
    size_t rowbase = (size_t)bb * S_;

    const u16* qrow = qbuf + (rowbase + q0 + q) * 256 + hh * 32;
    bf16x8 qf0 = *(const bf16x8*)(qrow + h * 8);
    bf16x8 qf1 = *(const bf16x8*)(qrow + 16 + h * 8);

    const u16* kb = ktiles + (size_t)(bb * 8 + hh) * 32768 + q * 32 + h * 8;
    const u16* vb = vtiles + (size_t)(bb * 8 + hh) * 32768 + q * 32 + h * 8;

    f32x16 O = {0.f, 0.f, 0.f, 0.f, 0.f, 0.f, 0.f, 0.f, 0.f, 0.f, 0.f, 0.f, 0.f, 0.f, 0.f, 0.f};
    float l = 0.f;

#define LOADT(d0, d1, d2, d3, t)                         \
    {                                                    \
        const u16* kr = kb + (t) * 1024;                 \
        d0 = *(const bf16x8*)kr;                         \
        d1 = *(const bf16x8*)(kr + 16);                  \
        const u16* vr = vb + (t) * 1024;                 \
        d2 = *(const bf16x8*)vr;                         \
        d3 = *(const bf16x8*)(vr + 16);                  \
    }

#define TILE_BODY(kf0_, kf1_, vf0_, vf1_)                                               \
    {                                                                                   \
        f32x16 S = {0.f, 0.f, 0.f, 0.f, 0.f, 0.f, 0.f, 0.f,                             \
                    0.f, 0.f, 0.f, 0.f, 0.f, 0.f, 0.f, 0.f};                            \
        __builtin_amdgcn_s_setprio(1);                                                  \
        S = __builtin_amdgcn_mfma_f32_32x32x16_bf16(kf0_, qf0, S, 0, 0, 0);             \
        S = __builtin_amdgcn_mfma_f32_32x32x16_bf16(kf1_, qf1, S, 0, 0, 0);             \
        __builtin_amdgcn_s_setprio(0);                                                  \
        _Pragma("unroll") for (int i = 0; i < 16; ++i) S[i] = fexp2(S[i]);              \
        float t0 = (S[0] + S[1]) + (S[2] + S[3]);                                       \
        float t1 = (S[4] + S[5]) + (S[6] + S[7]);                                       \
        float t2 = (S[8] + S[9]) + (S[10] + S[11]);                                     \
        float t3 = (S[12] + S[13]) + (S[14] + S[15]);                                   \
        float ls = (t0 + t1) + (t2 + t3);                                               \
        unsigned ua = __float_as_uint(ls), ub = ua;                                     \
        pl32swap(ua, ub);                                                               \
        l += __uint_as_float(ua) + __uint_as_float(ub);                                 \
        unsigned pk[8];                                                                 \
        _Pragma("unroll") for (int i = 0; i < 8; ++i) pk[i] = cvtpk(S[2 * i], S[2 * i + 1]); \
        pl32swap(pk[2], pk[0]);                                                         \
        pl32swap(pk[3], pk[1]);                                                         \
        pl32swap(pk[6], pk[4]);                                                         \
        pl32swap(pk[7], pk[5]);                                                         \
        uint4 t4 = {pk[0], pk[1], pk[2], pk[3]};                                        \
        uint4 t5 = {pk[4], pk[5], pk[6], pk[7]};                                        \
        bf16x8 pf0 = *(bf16x8*)&t4;                                                     \
        bf16x8 pf1 = *(bf16x8*)&t5;                                                     \
        __builtin_amdgcn_s_setprio(1);                                                  \
        O = __builtin_amdgcn_mfma_f32_32x32x16_bf16(vf0_, pf0, O, 0, 0, 0);             \
        O = __builtin_amdgcn_mfma_f32_32x32x16_bf16(vf1_, pf1, O, 0, 0, 0);             \
        __builtin_amdgcn_s_setprio(0);                                                  \
    }

    bf16x8 ka0, ka1, va0, va1, kb0, kb1, vb0, vb1;
    LOADT(ka0, ka1, va0, va1, 0);
    LOADT(kb0, kb1, vb0, vb1, 1);
    for (int kt = 0; kt < 32; kt += 2) {
        bf16x8 kc0 = ka0, kc1 = ka1, vc0 = va0, vc1 = va1;
        if (kt + 2 < 32) LOADT(kc0, kc1, vc0, vc1, kt + 2);
        TILE_BODY(ka0, ka1, va0, va1);
        bf16x8 kd0 = kb0, kd1 = kb1, vd0 = vb0, vd1 = vb1;
        if (kt + 3 < 32) LOADT(kd0, kd1, vd0, vd1, kt + 3);
        TILE_BODY(kb0, kb1, vb0, vb1);
        ka0 = kc0; ka1 = kc1; va0 = vc0; va1 = vc1;
        kb0 = kd0; kb1 = kd1; vb0 = vd0; vb1 = vd1;
    }
#undef LOADT
#undef TILE_BODY

    float inv = 1.f / l;
    u16* orow = qbuf + (rowbase + q0 + q) * 256 + hh * 32;
#pragma unroll
    for (int gg = 0; gg < 4; ++gg) {
        unsigned u0 = cvtpk(O[4 * gg] * inv, O[4 * gg + 1] * inv);
        unsigned u1 = cvtpk(O[4 * gg + 2] * inv, O[4 * gg + 3] * inv);
        uint2 val = {u0, u1};
        *(uint2*)(orow + gg * 8 + h * 4) = val;
    }
}

// ---------------- classifier from pooled sums ----------------
__global__ __launch_bounds__(256) void cls_kernel(const float* __restrict__ pooled,
                                                  const float* __restrict__ w1,
                                                  const float* __restrict__ b1,
                                                  const float* __restrict__ w2,
                                                  const float* __restrict__ b2,
                                                  float* __restrict__ out) {
    int b = blockIdx.x;
    int d = threadIdx.x;
    __shared__ float pl[256];
    __shared__ float hid[128];
    pl[d] = pooled[b * 256 + d] * (1.f / 1024.f);
    __syncthreads();
    if (d < 128) {
        float a = b1[d];
        for (int k = 0; k < 256; ++k) a += pl[k] * w1[k * 128 + d];
        hid[d] = fmaxf(a, 0.f);
    }
    __syncthreads();
    if (d == 0) {
        float a = b2[0];
        for (int k = 0; k < 128; ++k) a += hid[k] * w2[k];
        out[b] = 1.f / (1.f + expf(-a));
    }
}

extern "C" void kernel_launch(void* const* d_in, const int* in_sizes, int n_in,
                              void* d_out, int out_size, void* d_ws, size_t ws_size,
                              hipStream_t stream) {
    const float* x       = (const float*)d_in[0];
    const float* conv1_w = (const float*)d_in[1];
    const float* conv1_b = (const float*)d_in[2];
    const float* conv2_w = (const float*)d_in[3];
    const float* conv2_b = (const float*)d_in[4];
    const float* wq      = (const float*)d_in[5];
    const float* bq      = (const float*)d_in[6];
    const float* wk      = (const float*)d_in[7];
    const float* bk      = (const float*)d_in[8];
    const float* wv      = (const float*)d_in[9];
    const float* bv      = (const float*)d_in[10];
    const float* wo      = (const float*)d_in[11];
    const float* bo      = (const float*)d_in[12];
    const float* ln1_g   = (const float*)d_in[13];
    const float* ln1_b   = (const float*)d_in[14];
    const float* ff_w1   = (const float*)d_in[15];
    const float* ff_b1   = (const float*)d_in[16];
    const float* ff_w2   = (const float*)d_in[17];
    const float* ff_b2   = (const float*)d_in[18];
    const float* ln2_g   = (const float*)d_in[19];
    const float* ln2_b   = (const float*)d_in[20];
    const float* cls_w1  = (const float*)d_in[21];
    const float* cls_b1  = (const float*)d_in[22];
    const float* cls_w2  = (const float*)d_in[23];
    const float* cls_b2  = (const float*)d_in[24];

    char* wsb = (char*)d_ws;
    float* h    = (float*)wsb;
    u16*   hb   = (u16*)(wsb + ((size_t)16 << 20));
    u16*   qbuf = (u16*)(wsb + ((size_t)24 << 20));
    u16*   ktl  = (u16*)(wsb + ((size_t)32 << 20));
    u16*   vtl  = (u16*)(wsb + ((size_t)40 << 20));
    u16*   A2   = (u16*)(wsb + ((size_t)32 << 20));   // conv scratch (dead after conv2 gemm)
    float* pe   = (float*)(wsb + ((size_t)48 << 20));
    char*  pkb  = wsb + ((size_t)49 << 20);
    u16*   qkvT = (u16*)pkb;
    u16*   woT  = qkvT + (size_t)4 * 768 * 256;
    u16*   ff1T = woT + (size_t)4 * 256 * 256;
    u16*   ff2T = ff1T + (size_t)4 * 512 * 256;
    u16*   w2cT = ff2T + (size_t)4 * 512 * 256;
    float* bqkv = (float*)(w2cT + 256 * 128);
    float* pooled = bqkv + 4 * 768;

    // fold 1/sqrt(32) * log2(e) into Wq/bq (softmax in exp2 domain)
    const float qscale = 0.17677669529663687f * 1.4426950408889634f;
    pack_all<<<9372, 256, 0, stream>>>(wq, wk, wv, wo, ff_w1, ff_w2, conv2_w, bq, bk, bv,
                                       qkvT, woT, ff1T, ff2T, w2cT, pe, bqkv, pooled, qscale);

    conv1_im2col_kernel<<<8192, 256, 0, stream>>>(x, conv1_w, conv1_b, A2);
    mfma_gemm128<2, 2><<<256, 256, 0, stream>>>(A2, 128, w2cT, conv2_b, pe, h, hb,
                                                nullptr, nullptr, 256, 128);

    for (int l = 0; l < NL_; ++l) {
        const u16* qkvT_l = qkvT + (size_t)l * 768 * 256;
        const u16* woT_l  = woT + (size_t)l * 256 * 256;
        const u16* ff1T_l = ff1T + (size_t)l * 512 * 256;
        const u16* ff2T_l = ff2T + (size_t)l * 256 * 512;

        mfma_gemm128<3, 6><<<768, 256, 0, stream>>>(hb, 256, qkvT_l, bqkv + l * 768,
                                                    nullptr, nullptr, qbuf, ktl, vtl, 256, 256);
        attn_mfma<<<1024, 256, 0, stream>>>(qbuf, ktl, vtl);
        mfma_gemm_ln<<<512, 256, 0, stream>>>(qbuf, 256, woT_l, bo + l * 256, h,
                                              ln1_g + l * 256, ln1_b + l * 256, h, hb, 256);
        if (l < NL_ - 1) {
            fused_ff<0><<<512, 256, 0, stream>>>(hb, ff1T_l, ff_b1 + l * 512, ff2T_l,
                                                 ff_b2 + l * 256, h, ln2_g + l * 256,
                                                 ln2_b + l * 256, h, hb, nullptr);
        } else {
            fused_ff<1><<<512, 256, 0, stream>>>(hb, ff1T_l, ff_b1 + l * 512, ff2T_l,
                                                 ff_b2 + l * 256, h, ln2_g + l * 256,
                                                 ln2_b + l * 256, h, hb, pooled);
        }
    }

    cls_kernel<<<B_, 256, 0, stream>>>(pooled, cls_w1, cls_b1, cls_w2, cls_b2, (float*)d_out);
}